// Round 11
// baseline (402.041 us; speedup 1.0000x reference)
//
#include <hip/hip_runtime.h>
#include <hip/hip_bf16.h>
#include <stdint.h>

using bf16 = __hip_bfloat16;
typedef __attribute__((ext_vector_type(8))) short   short8;
typedef __attribute__((ext_vector_type(4))) float   floatx4;

static __device__ __forceinline__ unsigned short f2bf(float f) {
    return __builtin_bit_cast(unsigned short, __float2bfloat16(f));
}

// 8 consecutive elements at element-offset e as packed bf16 (f=1: fp32 cvt).
static __device__ __forceinline__ uint4 load8bf(const void* p, size_t e, int f) {
    if (!f) return *(const uint4*)((const ushort*)p + e);
    const float* fp = (const float*)p + e;
    float4 a = *(const float4*)fp;
    float4 b = *(const float4*)(fp + 4);
    union { uint4 u; unsigned short s[8]; } r;
    r.s[0] = f2bf(a.x); r.s[1] = f2bf(a.y); r.s[2] = f2bf(a.z); r.s[3] = f2bf(a.w);
    r.s[4] = f2bf(b.x); r.s[5] = f2bf(b.y); r.s[6] = f2bf(b.z); r.s[7] = f2bf(b.w);
    return r.u;
}
static __device__ __forceinline__ float loadScalar(const void* p, int i, int f) {
    return f ? ((const float*)p)[i] : __bfloat162float(((const bf16*)p)[i]);
}

// ---------------------------------------------------------------------------
__global__ void detect_dtype(const ushort* __restrict__ x, int* __restrict__ flag) {
    __shared__ int cnt;
    if (threadIdx.x == 0) cnt = 0;
    __syncthreads();
    unsigned short u = x[threadIdx.x * 2];
    int e = (u >> 7) & 0xFF;
    int bad = (e > 133 || e < 94) ? 1 : 0;
    atomicAdd(&cnt, bad);
    __syncthreads();
    if (threadIdx.x == 0) *flag = (cnt > 64) ? 1 : 0;
}

// ---------------------------------------------------------------------------
// NT GEMM: 512 thr / 8 waves, 128m x 64n tile, BK=64, 2-DEEP register
// prefetch + double-buffered XOR-swizzled LDS, ONE barrier per iter.
// 2-deep: latency tolerance ~2 compute-iters (~1000 cyc) >= HBM latency,
// attacking the vmcnt drain the 1-deep R10 version still paid.
// pm: 0 row-major [M,1024]; 1 scatter bf16 [B,H,S,D];
//     2 V^T [B,H,D,S] via LDS transpose, full-line stores (s-off m0&2047).
// ---------------------------------------------------------------------------
__global__ __launch_bounds__(512, 4)
void gemm_bt(const void* __restrict__ A, const void* __restrict__ W,
             const void* __restrict__ Bi, void* __restrict__ Out,
             int pm, int a_ext, int out_ext, const int* __restrict__ flagp)
{
    __shared__ ushort pool[24576];   // 48 KB: As dbuf 2x16KB, Ws dbuf 2x8KB

    const int f  = *flagp;
    const int fA = a_ext ? f : 0;

    const int n0 = blockIdx.x * 64;
    const int m0 = blockIdx.y * 128;
    const int tid  = threadIdx.x;
    const int lane = tid & 63;
    const int wave = tid >> 6;              // 0..7, owns m-rows wave*16..+15
    const int r15  = lane & 15;
    const int quad = lane >> 4;

    const int srow = tid >> 3;              // staging row 0..63
    const int sg   = tid & 7;               // staging 8-elem group

    floatx4 acc[4];
#pragma unroll
    for (int db = 0; db < 4; db++) acc[db] = (floatx4){0.f, 0.f, 0.f, 0.f};

    // 2-deep prefetch: slot s holds data for iter (it) with it&1 == s
    uint4 apre[2][2], wpre[2];
#pragma unroll
    for (int s = 0; s < 2; s++) {
#pragma unroll
        for (int p = 0; p < 2; p++)
            apre[s][p] = load8bf(A, (size_t)(m0 + srow + p * 64) * 1024
                                     + s * 64 + sg * 8, fA);
        wpre[s] = load8bf(W, (size_t)(n0 + srow) * 1024 + s * 64 + sg * 8, f);
    }

    for (int kb = 0; kb < 1024; kb += 64) {
        int sl = (kb >> 6) & 1;
        ushort* xs  = pool + sl * 8192;
        ushort* wsm = pool + 16384 + sl * 4096;
#pragma unroll
        for (int p = 0; p < 2; p++) {
            int row = srow + p * 64;
            *(uint4*)(&xs[row * 64 + ((sg ^ (row & 7)) << 3)]) = apre[sl][p];
        }
        *(uint4*)(&wsm[srow * 64 + ((sg ^ (srow & 7)) << 3)]) = wpre[sl];
        __syncthreads();
        if (kb + 128 < 1024) {
#pragma unroll
            for (int p = 0; p < 2; p++)
                apre[sl][p] = load8bf(A, (size_t)(m0 + srow + p * 64) * 1024
                                          + kb + 128 + sg * 8, fA);
            wpre[sl] = load8bf(W, (size_t)(n0 + srow) * 1024 + kb + 128 + sg * 8, f);
        }
#pragma unroll
        for (int ks = 0; ks < 2; ks++) {
            int arow = wave * 16 + r15;
            short8 af = *(const short8*)(
                &xs[arow * 64 + (((ks * 4 + quad) ^ (arow & 7)) << 3)]);
#pragma unroll
            for (int db = 0; db < 4; db++) {
                int brow = db * 16 + r15;
                short8 bv = *(const short8*)(
                    &wsm[brow * 64 + (((ks * 4 + quad) ^ (brow & 7)) << 3)]);
                acc[db] = __builtin_amdgcn_mfma_f32_16x16x32_bf16(
                    af, bv, acc[db], 0, 0, 0);
            }
        }
    }

    // C/D layout: col = lane&15, row = quad*4 + r (m89/m91)
    if (pm == 2) {
        // ---- V^T epilogue: acc -> LDS T[64 d][128 s] (swizzled) -> global ----
        __syncthreads();                    // all K-loop LDS reads done
#pragma unroll
        for (int db = 0; db < 4; db++) {
            int d = db * 16 + r15;
            float bias = loadScalar(Bi, n0 + d, f);
            int s4 = wave * 16 + quad * 4;  // s local, 4-aligned
            union { uint2 u; ushort us[4]; } pk;
#pragma unroll
            for (int r = 0; r < 4; r++) pk.us[r] = f2bf(acc[db][r] + bias);
            *(uint2*)(&pool[d * 128 + (((s4 >> 3) ^ (d & 15)) << 3) + (s4 & 7)])
                = pk.u;
        }
        __syncthreads();
        const int b_  = m0 >> 11;
        const int h   = n0 >> 6;
        const int sl0 = m0 & 2047;          // s-offset within batch
#pragma unroll
        for (int rr = 0; rr < 2; rr++) {
            int idx = rr * 512 + tid;       // 0..1023
            int d = idx >> 4, sgrp = idx & 15;
            uint4 v = *(const uint4*)(&pool[d * 128 + ((sgrp ^ (d & 15)) << 3)]);
            *(uint4*)((ushort*)Out +
                      ((size_t)((b_ * 16 + h) * 64 + d) << 11) + sl0 + sgrp * 8) = v;
        }
        return;
    }

#pragma unroll
    for (int db = 0; db < 4; db++) {
        int col = n0 + db * 16 + r15;
        float bias = loadScalar(Bi, col, f);
#pragma unroll
        for (int r = 0; r < 4; r++) {
            int row = m0 + wave * 16 + quad * 4 + r;
            float v = acc[db][r] + bias;
            if (pm == 1) {
                int h = col >> 6, d = col & 63;
                int b_ = row >> 11, s = row & 2047;
                ((ushort*)Out)[(((size_t)(b_ * 16 + h) * 2048 + s) << 6) + d]
                    = f2bf(v);
            } else if (out_ext && f) {
                ((float*)Out)[(size_t)row * 1024 + col] = v;
            } else {
                ((ushort*)Out)[(size_t)row * 1024 + col] = f2bf(v);
            }
        }
    }
}

// ---------------------------------------------------------------------------
// Fused Q-projection + flash attention (R7/R10 structure — measured 81 µs,
// UNCHANGED).  512 thr / 8 waves, 128 q/block, dbuf LDS, reg prefetch,
// ONE barrier per 64-key tile.  Fixed-max softmax (log2(e)/8 in Q),
// l via ones-MFMA, P truncation-packed through own-wave LDS rows.
// ---------------------------------------------------------------------------
__global__ __launch_bounds__(512, 4)
void attn_fused(const void* __restrict__ x, const void* __restrict__ Wq,
                const void* __restrict__ bq,
                const ushort* __restrict__ K, const ushort* __restrict__ VT,
                ushort* __restrict__ AO, const int* __restrict__ flagp)
{
    __shared__ ushort pool[24576];          // 48 KB

    const int f   = *flagp;
    const int bh  = blockIdx.y;
    const int h   = bh & 15, b_ = bh >> 4;
    const int q0  = blockIdx.x * 128;
    const int tid  = threadIdx.x;
    const int lane = tid & 63;
    const int wave = tid >> 6;              // 0..7, owns q rows wave*16..+15
    const int r15  = lane & 15;
    const int quad = lane >> 4;
    const size_t base = (size_t)bh << 17;

    const int srow = tid >> 3;              // staging row 0..63
    const int sg   = tid & 7;               // staging 8-elem group

    // ---- early prefetch: flash tile 0 (latency hidden under phase 1) ----
    uint4 kpre = *(const uint4*)(K  + base + (size_t)srow * 64   + sg * 8);
    uint4 vpre = *(const uint4*)(VT + base + (size_t)srow * 2048 + sg * 8);

    // ---------------- Phase 1: Q tile (128 q x 64 d), pipelined ----------
    floatx4 qacc[4];
#pragma unroll
    for (int db = 0; db < 4; db++) qacc[db] = (floatx4){0.f,0.f,0.f,0.f};

    uint4 xpre[2], wpre;
#pragma unroll
    for (int p = 0; p < 2; p++)
        xpre[p] = load8bf(x, (size_t)(b_ * 2048 + q0 + srow + p * 64) * 1024
                              + sg * 8, f);
    wpre = load8bf(Wq, (size_t)(h * 64 + srow) * 1024 + sg * 8, f);

    for (int kb = 0; kb < 1024; kb += 64) {
        int buf = (kb >> 6) & 1;
        ushort* xs  = pool + buf * 8192;
        ushort* wsm = pool + 16384 + buf * 4096;
#pragma unroll
        for (int p = 0; p < 2; p++) {
            int row = srow + p * 64;
            *(uint4*)(&xs[row * 64 + ((sg ^ (row & 7)) << 3)]) = xpre[p];
        }
        *(uint4*)(&wsm[srow * 64 + ((sg ^ (srow & 7)) << 3)]) = wpre;
        __syncthreads();
        if (kb + 64 < 1024) {
#pragma unroll
            for (int p = 0; p < 2; p++)
                xpre[p] = load8bf(x, (size_t)(b_ * 2048 + q0 + srow + p * 64) * 1024
                                      + kb + 64 + sg * 8, f);
            wpre = load8bf(Wq, (size_t)(h * 64 + srow) * 1024 + kb + 64 + sg * 8, f);
        }
#pragma unroll
        for (int ks = 0; ks < 2; ks++) {
            int arow = wave * 16 + r15;
            short8 af = *(const short8*)(
                &xs[arow * 64 + (((ks * 4 + quad) ^ (arow & 7)) << 3)]);
#pragma unroll
            for (int db = 0; db < 4; db++) {
                int brow = db * 16 + r15;
                short8 bv = *(const short8*)(
                    &wsm[brow * 64 + (((ks * 4 + quad) ^ (brow & 7)) << 3)]);
                qacc[db] = __builtin_amdgcn_mfma_f32_16x16x32_bf16(
                    af, bv, qacc[db], 0, 0, 0);
            }
        }
    }

    // Qs overlays xs0 (last compute used xs1; own-wave rows only)
    ushort* Qs = pool;
    const float csc = 0.1803368801f;        // log2(e)/8
#pragma unroll
    for (int db = 0; db < 4; db++) {
        int d = db * 16 + r15;
        float bias = loadScalar(bq, h * 64 + d, f);
#pragma unroll
        for (int r = 0; r < 4; r++) {
            int q = wave * 16 + quad * 4 + r;
            Qs[q * 64 + (((d >> 3) ^ (q & 7)) << 3) + (d & 7)] =
                f2bf((qacc[db][r] + bias) * csc);
        }
    }
    short8 qf[2];
#pragma unroll
    for (int ks = 0; ks < 2; ks++) {
        int arow = wave * 16 + r15;
        qf[ks] = *(const short8*)(
            &Qs[arow * 64 + (((ks * 4 + quad) ^ (arow & 7)) << 3)]);
    }
    __syncthreads();   // qf loaded + phase-1 reads done before pool reuse

    // ---------------- Phase 2: flash loop (1 barrier / tile) -------------
    floatx4 oacc[4], lacc;
#pragma unroll
    for (int db = 0; db < 4; db++) oacc[db] = (floatx4){0.f,0.f,0.f,0.f};
    lacc = (floatx4){0.f,0.f,0.f,0.f};
    short8 ones;
#pragma unroll
    for (int j = 0; j < 8; j++) ones[j] = (short)0x3F80;   // bf16 1.0
    ushort* Ps = pool + 16384;
    const int e7 = (r15 & 7) << 1;          // P swizzle key ((q&7)<<1)

    for (int t0 = 0; t0 < 2048; t0 += 64) {
        int buf = (t0 >> 6) & 1;
        ushort* Ks = pool + buf * 4096;
        ushort* Vt = pool + 8192 + buf * 4096;
        *(uint4*)(&Ks[srow * 64 + ((sg ^ (srow & 7)) << 3)]) = kpre;
        *(uint4*)(&Vt[srow * 64 + ((sg ^ (srow & 7)) << 3)]) = vpre;
        __syncthreads();
        if (t0 < 1984) {
            kpre = *(const uint4*)(K  + base + (size_t)(t0 + 64 + srow) * 64
                                       + sg * 8);
            vpre = *(const uint4*)(VT + base + (size_t)srow * 2048
                                       + t0 + 64 + sg * 8);
        }

        // S^T = K Q^T : rows = keys, cols = this wave's 16 queries
        floatx4 s[4];
#pragma unroll
        for (int mb = 0; mb < 4; mb++) s[mb] = (floatx4){0.f,0.f,0.f,0.f};
#pragma unroll
        for (int ks = 0; ks < 2; ks++)
#pragma unroll
            for (int mb = 0; mb < 4; mb++) {
                int arow = mb * 16 + r15;
                short8 kf = *(const short8*)(
                    &Ks[arow * 64 + (((ks * 4 + quad) ^ (arow & 7)) << 3)]);
                s[mb] = __builtin_amdgcn_mfma_f32_16x16x32_bf16(
                    kf, qf[ks], s[mb], 0, 0, 0);
            }

        // P = 2^S, truncation-packed pairs -> own-wave b64 writes
#pragma unroll
        for (int mb = 0; mb < 4; mb++) {
            int q  = wave * 16 + r15;
            int tg = (mb * 4 + quad) ^ e7;
            uint b0 = __builtin_bit_cast(uint, __builtin_amdgcn_exp2f(s[mb][0]));
            uint b1 = __builtin_bit_cast(uint, __builtin_amdgcn_exp2f(s[mb][1]));
            uint b2 = __builtin_bit_cast(uint, __builtin_amdgcn_exp2f(s[mb][2]));
            uint b3 = __builtin_bit_cast(uint, __builtin_amdgcn_exp2f(s[mb][3]));
            uint2 pk;
            pk.x = (b1 & 0xFFFF0000u) | (b0 >> 16);
            pk.y = (b3 & 0xFFFF0000u) | (b2 >> 16);
            *(uint2*)(&Ps[q * 64 + tg * 4]) = pk;
        }

        // O += P V^T, l += P·1
#pragma unroll
        for (int ks2 = 0; ks2 < 2; ks2++) {
            int q   = wave * 16 + r15;
            int tg0 = (ks2 * 8 + quad * 2) ^ e7;
            short8 pf = *(const short8*)(&Ps[q * 64 + tg0 * 4]);
#pragma unroll
            for (int db = 0; db < 4; db++) {
                int brow = db * 16 + r15;
                short8 vf = *(const short8*)(
                    &Vt[brow * 64 + (((ks2 * 4 + quad) ^ (brow & 7)) << 3)]);
                oacc[db] = __builtin_amdgcn_mfma_f32_16x16x32_bf16(
                    pf, vf, oacc[db], 0, 0, 0);
            }
            lacc = __builtin_amdgcn_mfma_f32_16x16x32_bf16(
                pf, ones, lacc, 0, 0, 0);
        }
    }

    // ---- epilogue: O / l -> AO [B,S,1024] bf16 ----
    float inv[4];
#pragma unroll
    for (int r = 0; r < 4; r++) inv[r] = 1.f / lacc[r];
#pragma unroll
    for (int db = 0; db < 4; db++) {
        int d = db * 16 + r15;
#pragma unroll
        for (int r = 0; r < 4; r++) {
            int qi = q0 + wave * 16 + quad * 4 + r;
            AO[((size_t)(b_ * 2048 + qi) << 10) + h * 64 + d] =
                f2bf(oacc[db][r] * inv[r]);
        }
    }
}

__global__ void copy_u4(const uint4* __restrict__ src, uint4* __restrict__ dst) {
    size_t i = (size_t)blockIdx.x * 256 + threadIdx.x;
    dst[i] = src[i];
}

// ---------------------------------------------------------------------------
extern "C" void kernel_launch(void* const* d_in, const int* in_sizes, int n_in,
                              void* d_out, int out_size, void* d_ws, size_t ws_size,
                              hipStream_t stream)
{
    const void* x  = d_in[0];
    const void* Wq = d_in[1];
    const void* bq = d_in[2];
    const void* Wk = d_in[3];
    const void* bk = d_in[4];
    const void* Wv = d_in[5];
    const void* bv = d_in[6];
    const void* Wo = d_in[7];
    const void* bo = d_in[8];

    // ws: [flag, pad 256B][Kw 8MB][Vw(V^T) 8MB][AOw 8MB if ws_size allows]
    const size_t TEN = (size_t)2 * 16 * 2048 * 64;   // 4 Mi elements (8 MB)
    int*    flagp = (int*)d_ws;
    ushort* Kw    = (ushort*)((char*)d_ws + 256);
    ushort* Vw    = Kw + TEN;
    const bool big_ws = ws_size >= 3 * TEN * sizeof(ushort) + 256;
    ushort* AOw   = big_ws ? (Vw + TEN) : (ushort*)d_out;
    ushort* Oin   = big_ws ? AOw : Kw;    // O-proj input (Kw reused if small ws)

    detect_dtype<<<1, 256, 0, stream>>>((const ushort*)x, flagp);

    // K -> Kw [B,H,S,D] (pm=1)
    gemm_bt<<<dim3(16, 32), dim3(512), 0, stream>>>(
        x, Wk, bk, Kw, /*pm=*/1, /*a_ext=*/1, /*out_ext=*/0, flagp);

    // V -> Vw [B,H,D,S] (pm=2, LDS transpose, full-line stores)
    gemm_bt<<<dim3(16, 32), dim3(512), 0, stream>>>(
        x, Wv, bv, Vw, /*pm=*/2, /*a_ext=*/1, /*out_ext=*/0, flagp);

    // fused Q-proj + attention -> AO (ws if it fits, else d_out staging)
    attn_fused<<<dim3(16, 32), dim3(512), 0, stream>>>(
        x, Wq, bq, Kw, Vw, AOw, flagp);

    // small-ws fallback: move AO out of d_out so O-proj is race-free
    if (!big_ws)
        copy_u4<<<dim3(2048), dim3(256), 0, stream>>>(
            (const uint4*)d_out, (uint4*)Oin);

    // O-projection -> final output (dtype per flag)
    gemm_bt<<<dim3(16, 32), dim3(512), 0, stream>>>(
        Oin, Wo, bo, d_out, /*pm=*/0, /*a_ext=*/0, /*out_ext=*/1, flagp);
}

// Round 12
// 256.445 us; speedup vs baseline: 1.5677x; 1.5677x over previous
//
#include <hip/hip_runtime.h>
#include <hip/hip_bf16.h>
#include <stdint.h>

using bf16 = __hip_bfloat16;
typedef __attribute__((ext_vector_type(8))) short   short8;
typedef __attribute__((ext_vector_type(4))) float   floatx4;

static __device__ __forceinline__ unsigned short f2bf(float f) {
    return __builtin_bit_cast(unsigned short, __float2bfloat16(f));
}

// 8 consecutive elements at element-offset e as packed bf16 (f=1: fp32 cvt).
static __device__ __forceinline__ uint4 load8bf(const void* p, size_t e, int f) {
    if (!f) return *(const uint4*)((const ushort*)p + e);
    const float* fp = (const float*)p + e;
    float4 a = *(const float4*)fp;
    float4 b = *(const float4*)(fp + 4);
    union { uint4 u; unsigned short s[8]; } r;
    r.s[0] = f2bf(a.x); r.s[1] = f2bf(a.y); r.s[2] = f2bf(a.z); r.s[3] = f2bf(a.w);
    r.s[4] = f2bf(b.x); r.s[5] = f2bf(b.y); r.s[6] = f2bf(b.z); r.s[7] = f2bf(b.w);
    return r.u;
}
static __device__ __forceinline__ float loadScalar(const void* p, int i, int f) {
    return f ? ((const float*)p)[i] : __bfloat162float(((const bf16*)p)[i]);
}

// ---------------------------------------------------------------------------
__global__ void detect_dtype(const ushort* __restrict__ x, int* __restrict__ flag) {
    __shared__ int cnt;
    if (threadIdx.x == 0) cnt = 0;
    __syncthreads();
    unsigned short u = x[threadIdx.x * 2];
    int e = (u >> 7) & 0xFF;
    int bad = (e > 133 || e < 94) ? 1 : 0;
    atomicAdd(&cnt, bad);
    __syncthreads();
    if (threadIdx.x == 0) *flag = (cnt > 64) ? 1 : 0;
}

// ---------------------------------------------------------------------------
// NT GEMM: 512 thr / 8 waves, 128m x 64n tile, BK=64, 2-deep register
// prefetch + double-buffered XOR-swizzled LDS, ONE barrier per iter.
// R11 lesson: `#pragma unroll 2` makes the prefetch-slot index compile-time
// constant (dynamic register-array indexing demotes to HBM-backed scratch:
// 340 MB traffic/dispatch, 103 µs); launch_bounds (512,2) not (512,4) — the
// 64-VGPR cap forced spills, and LDS (48 KB) caps residency at 3 blk/CU anyway.
// pm: 0 row-major [M,1024]; 1 scatter bf16 [B,H,S,D];
//     2 V^T [B,H,D,S] via LDS transpose, full-line stores (s-off m0&2047).
// ---------------------------------------------------------------------------
__global__ __launch_bounds__(512, 2)
void gemm_bt(const void* __restrict__ A, const void* __restrict__ W,
             const void* __restrict__ Bi, void* __restrict__ Out,
             int pm, int a_ext, int out_ext, const int* __restrict__ flagp)
{
    __shared__ ushort pool[24576];   // 48 KB: As dbuf 2x16KB, Ws dbuf 2x8KB

    const int f  = *flagp;
    const int fA = a_ext ? f : 0;

    const int n0 = blockIdx.x * 64;
    const int m0 = blockIdx.y * 128;
    const int tid  = threadIdx.x;
    const int lane = tid & 63;
    const int wave = tid >> 6;              // 0..7, owns m-rows wave*16..+15
    const int r15  = lane & 15;
    const int quad = lane >> 4;

    const int srow = tid >> 3;              // staging row 0..63
    const int sg   = tid & 7;               // staging 8-elem group

    floatx4 acc[4];
#pragma unroll
    for (int db = 0; db < 4; db++) acc[db] = (floatx4){0.f, 0.f, 0.f, 0.f};

    // 2-deep prefetch: slot s holds data for iter with (it&1)==s
    uint4 apre[2][2], wpre[2];
#pragma unroll
    for (int s = 0; s < 2; s++) {
#pragma unroll
        for (int p = 0; p < 2; p++)
            apre[s][p] = load8bf(A, (size_t)(m0 + srow + p * 64) * 1024
                                     + s * 64 + sg * 8, fA);
        wpre[s] = load8bf(W, (size_t)(n0 + srow) * 1024 + s * 64 + sg * 8, f);
    }

#pragma unroll 2
    for (int kb = 0; kb < 1024; kb += 64) {
        const int sl = (kb >> 6) & 1;       // compile-time under unroll-2
        ushort* xs  = pool + sl * 8192;
        ushort* wsm = pool + 16384 + sl * 4096;
#pragma unroll
        for (int p = 0; p < 2; p++) {
            int row = srow + p * 64;
            *(uint4*)(&xs[row * 64 + ((sg ^ (row & 7)) << 3)]) = apre[sl][p];
        }
        *(uint4*)(&wsm[srow * 64 + ((sg ^ (srow & 7)) << 3)]) = wpre[sl];
        __syncthreads();
        if (kb + 128 < 1024) {
#pragma unroll
            for (int p = 0; p < 2; p++)
                apre[sl][p] = load8bf(A, (size_t)(m0 + srow + p * 64) * 1024
                                          + kb + 128 + sg * 8, fA);
            wpre[sl] = load8bf(W, (size_t)(n0 + srow) * 1024 + kb + 128 + sg * 8, f);
        }
#pragma unroll
        for (int ks = 0; ks < 2; ks++) {
            int arow = wave * 16 + r15;
            short8 af = *(const short8*)(
                &xs[arow * 64 + (((ks * 4 + quad) ^ (arow & 7)) << 3)]);
#pragma unroll
            for (int db = 0; db < 4; db++) {
                int brow = db * 16 + r15;
                short8 bv = *(const short8*)(
                    &wsm[brow * 64 + (((ks * 4 + quad) ^ (brow & 7)) << 3)]);
                acc[db] = __builtin_amdgcn_mfma_f32_16x16x32_bf16(
                    af, bv, acc[db], 0, 0, 0);
            }
        }
    }

    // C/D layout: col = lane&15, row = quad*4 + r (m89/m91)
    if (pm == 2) {
        // ---- V^T epilogue: acc -> LDS T[64 d][128 s] (swizzled) -> global ----
        __syncthreads();                    // all K-loop LDS reads done
#pragma unroll
        for (int db = 0; db < 4; db++) {
            int d = db * 16 + r15;
            float bias = loadScalar(Bi, n0 + d, f);
            int s4 = wave * 16 + quad * 4;  // s local, 4-aligned
            union { uint2 u; ushort us[4]; } pk;
#pragma unroll
            for (int r = 0; r < 4; r++) pk.us[r] = f2bf(acc[db][r] + bias);
            *(uint2*)(&pool[d * 128 + (((s4 >> 3) ^ (d & 15)) << 3) + (s4 & 7)])
                = pk.u;
        }
        __syncthreads();
        const int b_  = m0 >> 11;
        const int h   = n0 >> 6;
        const int sl0 = m0 & 2047;          // s-offset within batch
#pragma unroll
        for (int rr = 0; rr < 2; rr++) {
            int idx = rr * 512 + tid;       // 0..1023
            int d = idx >> 4, sgrp = idx & 15;
            uint4 v = *(const uint4*)(&pool[d * 128 + ((sgrp ^ (d & 15)) << 3)]);
            *(uint4*)((ushort*)Out +
                      ((size_t)((b_ * 16 + h) * 64 + d) << 11) + sl0 + sgrp * 8) = v;
        }
        return;
    }

#pragma unroll
    for (int db = 0; db < 4; db++) {
        int col = n0 + db * 16 + r15;
        float bias = loadScalar(Bi, col, f);
#pragma unroll
        for (int r = 0; r < 4; r++) {
            int row = m0 + wave * 16 + quad * 4 + r;
            float v = acc[db][r] + bias;
            if (pm == 1) {
                int h = col >> 6, d = col & 63;
                int b_ = row >> 11, s = row & 2047;
                ((ushort*)Out)[(((size_t)(b_ * 16 + h) * 2048 + s) << 6) + d]
                    = f2bf(v);
            } else if (out_ext && f) {
                ((float*)Out)[(size_t)row * 1024 + col] = v;
            } else {
                ((ushort*)Out)[(size_t)row * 1024 + col] = f2bf(v);
            }
        }
    }
}

// ---------------------------------------------------------------------------
// Fused Q-projection + flash attention (R7/R10 structure — measured 81 µs,
// UNCHANGED).  512 thr / 8 waves, 128 q/block, dbuf LDS, reg prefetch,
// ONE barrier per 64-key tile.  Fixed-max softmax (log2(e)/8 in Q),
// l via ones-MFMA, P truncation-packed through own-wave LDS rows.
// ---------------------------------------------------------------------------
__global__ __launch_bounds__(512, 4)
void attn_fused(const void* __restrict__ x, const void* __restrict__ Wq,
                const void* __restrict__ bq,
                const ushort* __restrict__ K, const ushort* __restrict__ VT,
                ushort* __restrict__ AO, const int* __restrict__ flagp)
{
    __shared__ ushort pool[24576];          // 48 KB

    const int f   = *flagp;
    const int bh  = blockIdx.y;
    const int h   = bh & 15, b_ = bh >> 4;
    const int q0  = blockIdx.x * 128;
    const int tid  = threadIdx.x;
    const int lane = tid & 63;
    const int wave = tid >> 6;              // 0..7, owns q rows wave*16..+15
    const int r15  = lane & 15;
    const int quad = lane >> 4;
    const size_t base = (size_t)bh << 17;

    const int srow = tid >> 3;              // staging row 0..63
    const int sg   = tid & 7;               // staging 8-elem group

    // ---- early prefetch: flash tile 0 (latency hidden under phase 1) ----
    uint4 kpre = *(const uint4*)(K  + base + (size_t)srow * 64   + sg * 8);
    uint4 vpre = *(const uint4*)(VT + base + (size_t)srow * 2048 + sg * 8);

    // ---------------- Phase 1: Q tile (128 q x 64 d), pipelined ----------
    floatx4 qacc[4];
#pragma unroll
    for (int db = 0; db < 4; db++) qacc[db] = (floatx4){0.f,0.f,0.f,0.f};

    uint4 xpre[2], wpre;
#pragma unroll
    for (int p = 0; p < 2; p++)
        xpre[p] = load8bf(x, (size_t)(b_ * 2048 + q0 + srow + p * 64) * 1024
                              + sg * 8, f);
    wpre = load8bf(Wq, (size_t)(h * 64 + srow) * 1024 + sg * 8, f);

    for (int kb = 0; kb < 1024; kb += 64) {
        int buf = (kb >> 6) & 1;
        ushort* xs  = pool + buf * 8192;
        ushort* wsm = pool + 16384 + buf * 4096;
#pragma unroll
        for (int p = 0; p < 2; p++) {
            int row = srow + p * 64;
            *(uint4*)(&xs[row * 64 + ((sg ^ (row & 7)) << 3)]) = xpre[p];
        }
        *(uint4*)(&wsm[srow * 64 + ((sg ^ (srow & 7)) << 3)]) = wpre;
        __syncthreads();
        if (kb + 64 < 1024) {
#pragma unroll
            for (int p = 0; p < 2; p++)
                xpre[p] = load8bf(x, (size_t)(b_ * 2048 + q0 + srow + p * 64) * 1024
                                      + kb + 64 + sg * 8, f);
            wpre = load8bf(Wq, (size_t)(h * 64 + srow) * 1024 + kb + 64 + sg * 8, f);
        }
#pragma unroll
        for (int ks = 0; ks < 2; ks++) {
            int arow = wave * 16 + r15;
            short8 af = *(const short8*)(
                &xs[arow * 64 + (((ks * 4 + quad) ^ (arow & 7)) << 3)]);
#pragma unroll
            for (int db = 0; db < 4; db++) {
                int brow = db * 16 + r15;
                short8 bv = *(const short8*)(
                    &wsm[brow * 64 + (((ks * 4 + quad) ^ (brow & 7)) << 3)]);
                qacc[db] = __builtin_amdgcn_mfma_f32_16x16x32_bf16(
                    af, bv, qacc[db], 0, 0, 0);
            }
        }
    }

    // Qs overlays xs0 (last compute used xs1; own-wave rows only)
    ushort* Qs = pool;
    const float csc = 0.1803368801f;        // log2(e)/8
#pragma unroll
    for (int db = 0; db < 4; db++) {
        int d = db * 16 + r15;
        float bias = loadScalar(bq, h * 64 + d, f);
#pragma unroll
        for (int r = 0; r < 4; r++) {
            int q = wave * 16 + quad * 4 + r;
            Qs[q * 64 + (((d >> 3) ^ (q & 7)) << 3) + (d & 7)] =
                f2bf((qacc[db][r] + bias) * csc);
        }
    }
    short8 qf[2];
#pragma unroll
    for (int ks = 0; ks < 2; ks++) {
        int arow = wave * 16 + r15;
        qf[ks] = *(const short8*)(
            &Qs[arow * 64 + (((ks * 4 + quad) ^ (arow & 7)) << 3)]);
    }
    __syncthreads();   // qf loaded + phase-1 reads done before pool reuse

    // ---------------- Phase 2: flash loop (1 barrier / tile) -------------
    floatx4 oacc[4], lacc;
#pragma unroll
    for (int db = 0; db < 4; db++) oacc[db] = (floatx4){0.f,0.f,0.f,0.f};
    lacc = (floatx4){0.f,0.f,0.f,0.f};
    short8 ones;
#pragma unroll
    for (int j = 0; j < 8; j++) ones[j] = (short)0x3F80;   // bf16 1.0
    ushort* Ps = pool + 16384;
    const int e7 = (r15 & 7) << 1;          // P swizzle key ((q&7)<<1)

    for (int t0 = 0; t0 < 2048; t0 += 64) {
        int buf = (t0 >> 6) & 1;
        ushort* Ks = pool + buf * 4096;
        ushort* Vt = pool + 8192 + buf * 4096;
        *(uint4*)(&Ks[srow * 64 + ((sg ^ (srow & 7)) << 3)]) = kpre;
        *(uint4*)(&Vt[srow * 64 + ((sg ^ (srow & 7)) << 3)]) = vpre;
        __syncthreads();
        if (t0 < 1984) {
            kpre = *(const uint4*)(K  + base + (size_t)(t0 + 64 + srow) * 64
                                       + sg * 8);
            vpre = *(const uint4*)(VT + base + (size_t)srow * 2048
                                       + t0 + 64 + sg * 8);
        }

        // S^T = K Q^T : rows = keys, cols = this wave's 16 queries
        floatx4 s[4];
#pragma unroll
        for (int mb = 0; mb < 4; mb++) s[mb] = (floatx4){0.f,0.f,0.f,0.f};
#pragma unroll
        for (int ks = 0; ks < 2; ks++)
#pragma unroll
            for (int mb = 0; mb < 4; mb++) {
                int arow = mb * 16 + r15;
                short8 kf = *(const short8*)(
                    &Ks[arow * 64 + (((ks * 4 + quad) ^ (arow & 7)) << 3)]);
                s[mb] = __builtin_amdgcn_mfma_f32_16x16x32_bf16(
                    kf, qf[ks], s[mb], 0, 0, 0);
            }

        // P = 2^S, truncation-packed pairs -> own-wave b64 writes
#pragma unroll
        for (int mb = 0; mb < 4; mb++) {
            int q  = wave * 16 + r15;
            int tg = (mb * 4 + quad) ^ e7;
            uint b0 = __builtin_bit_cast(uint, __builtin_amdgcn_exp2f(s[mb][0]));
            uint b1 = __builtin_bit_cast(uint, __builtin_amdgcn_exp2f(s[mb][1]));
            uint b2 = __builtin_bit_cast(uint, __builtin_amdgcn_exp2f(s[mb][2]));
            uint b3 = __builtin_bit_cast(uint, __builtin_amdgcn_exp2f(s[mb][3]));
            uint2 pk;
            pk.x = (b1 & 0xFFFF0000u) | (b0 >> 16);
            pk.y = (b3 & 0xFFFF0000u) | (b2 >> 16);
            *(uint2*)(&Ps[q * 64 + tg * 4]) = pk;
        }

        // O += P V^T, l += P·1
#pragma unroll
        for (int ks2 = 0; ks2 < 2; ks2++) {
            int q   = wave * 16 + r15;
            int tg0 = (ks2 * 8 + quad * 2) ^ e7;
            short8 pf = *(const short8*)(&Ps[q * 64 + tg0 * 4]);
#pragma unroll
            for (int db = 0; db < 4; db++) {
                int brow = db * 16 + r15;
                short8 vf = *(const short8*)(
                    &Vt[brow * 64 + (((ks2 * 4 + quad) ^ (brow & 7)) << 3)]);
                oacc[db] = __builtin_amdgcn_mfma_f32_16x16x32_bf16(
                    pf, vf, oacc[db], 0, 0, 0);
            }
            lacc = __builtin_amdgcn_mfma_f32_16x16x32_bf16(
                pf, ones, lacc, 0, 0, 0);
        }
    }

    // ---- epilogue: O / l -> AO [B,S,1024] bf16 ----
    float inv[4];
#pragma unroll
    for (int r = 0; r < 4; r++) inv[r] = 1.f / lacc[r];
#pragma unroll
    for (int db = 0; db < 4; db++) {
        int d = db * 16 + r15;
#pragma unroll
        for (int r = 0; r < 4; r++) {
            int qi = q0 + wave * 16 + quad * 4 + r;
            AO[((size_t)(b_ * 2048 + qi) << 10) + h * 64 + d] =
                f2bf(oacc[db][r] * inv[r]);
        }
    }
}

__global__ void copy_u4(const uint4* __restrict__ src, uint4* __restrict__ dst) {
    size_t i = (size_t)blockIdx.x * 256 + threadIdx.x;
    dst[i] = src[i];
}

// ---------------------------------------------------------------------------
extern "C" void kernel_launch(void* const* d_in, const int* in_sizes, int n_in,
                              void* d_out, int out_size, void* d_ws, size_t ws_size,
                              hipStream_t stream)
{
    const void* x  = d_in[0];
    const void* Wq = d_in[1];
    const void* bq = d_in[2];
    const void* Wk = d_in[3];
    const void* bk = d_in[4];
    const void* Wv = d_in[5];
    const void* bv = d_in[6];
    const void* Wo = d_in[7];
    const void* bo = d_in[8];

    // ws: [flag, pad 256B][Kw 8MB][Vw(V^T) 8MB][AOw 8MB if ws_size allows]
    const size_t TEN = (size_t)2 * 16 * 2048 * 64;   // 4 Mi elements (8 MB)
    int*    flagp = (int*)d_ws;
    ushort* Kw    = (ushort*)((char*)d_ws + 256);
    ushort* Vw    = Kw + TEN;
    const bool big_ws = ws_size >= 3 * TEN * sizeof(ushort) + 256;
    ushort* AOw   = big_ws ? (Vw + TEN) : (ushort*)d_out;
    ushort* Oin   = big_ws ? AOw : Kw;    // O-proj input (Kw reused if small ws)

    detect_dtype<<<1, 256, 0, stream>>>((const ushort*)x, flagp);

    // K -> Kw [B,H,S,D] (pm=1)
    gemm_bt<<<dim3(16, 32), dim3(512), 0, stream>>>(
        x, Wk, bk, Kw, /*pm=*/1, /*a_ext=*/1, /*out_ext=*/0, flagp);

    // V -> Vw [B,H,D,S] (pm=2, LDS transpose, full-line stores)
    gemm_bt<<<dim3(16, 32), dim3(512), 0, stream>>>(
        x, Wv, bv, Vw, /*pm=*/2, /*a_ext=*/1, /*out_ext=*/0, flagp);

    // fused Q-proj + attention -> AO (ws if it fits, else d_out staging)
    attn_fused<<<dim3(16, 32), dim3(512), 0, stream>>>(
        x, Wq, bq, Kw, Vw, AOw, flagp);

    // small-ws fallback: move AO out of d_out so O-proj is race-free
    if (!big_ws)
        copy_u4<<<dim3(2048), dim3(256), 0, stream>>>(
            (const uint4*)d_out, (uint4*)Oin);

    // O-projection -> final output (dtype per flag)
    gemm_bt<<<dim3(16, 32), dim3(512), 0, stream>>>(
        Oin, Wo, bo, d_out, /*pm=*/0, /*a_ext=*/0, /*out_ext=*/1, flagp);
}

// Round 13
// 242.123 us; speedup vs baseline: 1.6605x; 1.0591x over previous
//
#include <hip/hip_runtime.h>
#include <hip/hip_bf16.h>
#include <stdint.h>

using bf16 = __hip_bfloat16;
typedef __attribute__((ext_vector_type(8))) short   short8;
typedef __attribute__((ext_vector_type(4))) float   floatx4;

static __device__ __forceinline__ unsigned short f2bf(float f) {
    return __builtin_bit_cast(unsigned short, __float2bfloat16(f));
}

// 8 consecutive elements at element-offset e as packed bf16 (f=1: fp32 cvt).
static __device__ __forceinline__ uint4 load8bf(const void* p, size_t e, int f) {
    if (!f) return *(const uint4*)((const ushort*)p + e);
    const float* fp = (const float*)p + e;
    float4 a = *(const float4*)fp;
    float4 b = *(const float4*)(fp + 4);
    union { uint4 u; unsigned short s[8]; } r;
    r.s[0] = f2bf(a.x); r.s[1] = f2bf(a.y); r.s[2] = f2bf(a.z); r.s[3] = f2bf(a.w);
    r.s[4] = f2bf(b.x); r.s[5] = f2bf(b.y); r.s[6] = f2bf(b.z); r.s[7] = f2bf(b.w);
    return r.u;
}
static __device__ __forceinline__ float loadScalar(const void* p, int i, int f) {
    return f ? ((const float*)p)[i] : __bfloat162float(((const bf16*)p)[i]);
}

// ---------------------------------------------------------------------------
__global__ void detect_dtype(const ushort* __restrict__ x, int* __restrict__ flag) {
    __shared__ int cnt;
    if (threadIdx.x == 0) cnt = 0;
    __syncthreads();
    unsigned short u = x[threadIdx.x * 2];
    int e = (u >> 7) & 0xFF;
    int bad = (e > 133 || e < 94) ? 1 : 0;
    atomicAdd(&cnt, bad);
    __syncthreads();
    if (threadIdx.x == 0) *flag = (cnt > 64) ? 1 : 0;
}

// ---------------------------------------------------------------------------
// NT GEMM: 512 thr / 8 waves, 128m x 64n tile, BK=64, 2-deep register
// prefetch + double-buffered XOR-swizzled LDS, ONE barrier per iter.
// R13 change: grid is (x = m-tile, y = n-tile).  With round-robin block->XCD
// dispatch (linear%8), same-m0 blocks (linear stride 32 == 0 mod 8) land on
// ONE XCD, so the shared 256KB A-tile + 2MB W stay in that XCD's 4MB L2.
// The old (x=n, y=m) mapping spread the 16 A-sharers over all 8 XCDs ->
// ~150MB L2-miss traffic/dispatch (R11: FETCH 126MB) -> fetch-bound 53 µs.
// pm: 0 row-major [M,1024]; 1 scatter bf16 [B,H,S,D];
//     2 V^T [B,H,D,S] via LDS transpose, full-line stores (s-off m0&2047).
// ---------------------------------------------------------------------------
__global__ __launch_bounds__(512, 2)
void gemm_bt(const void* __restrict__ A, const void* __restrict__ W,
             const void* __restrict__ Bi, void* __restrict__ Out,
             int pm, int a_ext, int out_ext, const int* __restrict__ flagp)
{
    __shared__ ushort pool[24576];   // 48 KB: As dbuf 2x16KB, Ws dbuf 2x8KB

    const int f  = *flagp;
    const int fA = a_ext ? f : 0;

    const int m0 = blockIdx.x * 128;        // x = m-tile (32 values)
    const int n0 = blockIdx.y * 64;         // y = n-tile (16 values)
    const int tid  = threadIdx.x;
    const int lane = tid & 63;
    const int wave = tid >> 6;              // 0..7, owns m-rows wave*16..+15
    const int r15  = lane & 15;
    const int quad = lane >> 4;

    const int srow = tid >> 3;              // staging row 0..63
    const int sg   = tid & 7;               // staging 8-elem group

    floatx4 acc[4];
#pragma unroll
    for (int db = 0; db < 4; db++) acc[db] = (floatx4){0.f, 0.f, 0.f, 0.f};

    // 2-deep prefetch: slot s holds data for iter with (it&1)==s
    uint4 apre[2][2], wpre[2];
#pragma unroll
    for (int s = 0; s < 2; s++) {
#pragma unroll
        for (int p = 0; p < 2; p++)
            apre[s][p] = load8bf(A, (size_t)(m0 + srow + p * 64) * 1024
                                     + s * 64 + sg * 8, fA);
        wpre[s] = load8bf(W, (size_t)(n0 + srow) * 1024 + s * 64 + sg * 8, f);
    }

#pragma unroll 2
    for (int kb = 0; kb < 1024; kb += 64) {
        const int sl = (kb >> 6) & 1;       // compile-time under unroll-2
        ushort* xs  = pool + sl * 8192;
        ushort* wsm = pool + 16384 + sl * 4096;
#pragma unroll
        for (int p = 0; p < 2; p++) {
            int row = srow + p * 64;
            *(uint4*)(&xs[row * 64 + ((sg ^ (row & 7)) << 3)]) = apre[sl][p];
        }
        *(uint4*)(&wsm[srow * 64 + ((sg ^ (srow & 7)) << 3)]) = wpre[sl];
        __syncthreads();
        if (kb + 128 < 1024) {
#pragma unroll
            for (int p = 0; p < 2; p++)
                apre[sl][p] = load8bf(A, (size_t)(m0 + srow + p * 64) * 1024
                                          + kb + 128 + sg * 8, fA);
            wpre[sl] = load8bf(W, (size_t)(n0 + srow) * 1024 + kb + 128 + sg * 8, f);
        }
#pragma unroll
        for (int ks = 0; ks < 2; ks++) {
            int arow = wave * 16 + r15;
            short8 af = *(const short8*)(
                &xs[arow * 64 + (((ks * 4 + quad) ^ (arow & 7)) << 3)]);
#pragma unroll
            for (int db = 0; db < 4; db++) {
                int brow = db * 16 + r15;
                short8 bv = *(const short8*)(
                    &wsm[brow * 64 + (((ks * 4 + quad) ^ (brow & 7)) << 3)]);
                acc[db] = __builtin_amdgcn_mfma_f32_16x16x32_bf16(
                    af, bv, acc[db], 0, 0, 0);
            }
        }
    }

    // C/D layout: col = lane&15, row = quad*4 + r (m89/m91)
    if (pm == 2) {
        // ---- V^T epilogue: acc -> LDS T[64 d][128 s] (swizzled) -> global ----
        __syncthreads();                    // all K-loop LDS reads done
#pragma unroll
        for (int db = 0; db < 4; db++) {
            int d = db * 16 + r15;
            float bias = loadScalar(Bi, n0 + d, f);
            int s4 = wave * 16 + quad * 4;  // s local, 4-aligned
            union { uint2 u; ushort us[4]; } pk;
#pragma unroll
            for (int r = 0; r < 4; r++) pk.us[r] = f2bf(acc[db][r] + bias);
            *(uint2*)(&pool[d * 128 + (((s4 >> 3) ^ (d & 15)) << 3) + (s4 & 7)])
                = pk.u;
        }
        __syncthreads();
        const int b_  = m0 >> 11;
        const int h   = n0 >> 6;
        const int sl0 = m0 & 2047;          // s-offset within batch
#pragma unroll
        for (int rr = 0; rr < 2; rr++) {
            int idx = rr * 512 + tid;       // 0..1023
            int d = idx >> 4, sgrp = idx & 15;
            uint4 v = *(const uint4*)(&pool[d * 128 + ((sgrp ^ (d & 15)) << 3)]);
            *(uint4*)((ushort*)Out +
                      ((size_t)((b_ * 16 + h) * 64 + d) << 11) + sl0 + sgrp * 8) = v;
        }
        return;
    }

#pragma unroll
    for (int db = 0; db < 4; db++) {
        int col = n0 + db * 16 + r15;
        float bias = loadScalar(Bi, col, f);
#pragma unroll
        for (int r = 0; r < 4; r++) {
            int row = m0 + wave * 16 + quad * 4 + r;
            float v = acc[db][r] + bias;
            if (pm == 1) {
                int h = col >> 6, d = col & 63;
                int b_ = row >> 11, s = row & 2047;
                ((ushort*)Out)[(((size_t)(b_ * 16 + h) * 2048 + s) << 6) + d]
                    = f2bf(v);
            } else if (out_ext && f) {
                ((float*)Out)[(size_t)row * 1024 + col] = v;
            } else {
                ((ushort*)Out)[(size_t)row * 1024 + col] = f2bf(v);
            }
        }
    }
}

// ---------------------------------------------------------------------------
// Fused Q-projection + flash attention (R7/R10 structure — measured ~82 µs,
// UNCHANGED).  512 thr / 8 waves, 128 q/block, dbuf LDS, reg prefetch,
// ONE barrier per 64-key tile.  Fixed-max softmax (log2(e)/8 in Q),
// l via ones-MFMA, P truncation-packed through own-wave LDS rows.
// ---------------------------------------------------------------------------
__global__ __launch_bounds__(512, 4)
void attn_fused(const void* __restrict__ x, const void* __restrict__ Wq,
                const void* __restrict__ bq,
                const ushort* __restrict__ K, const ushort* __restrict__ VT,
                ushort* __restrict__ AO, const int* __restrict__ flagp)
{
    __shared__ ushort pool[24576];          // 48 KB

    const int f   = *flagp;
    const int bh  = blockIdx.y;
    const int h   = bh & 15, b_ = bh >> 4;
    const int q0  = blockIdx.x * 128;
    const int tid  = threadIdx.x;
    const int lane = tid & 63;
    const int wave = tid >> 6;              // 0..7, owns q rows wave*16..+15
    const int r15  = lane & 15;
    const int quad = lane >> 4;
    const size_t base = (size_t)bh << 17;

    const int srow = tid >> 3;              // staging row 0..63
    const int sg   = tid & 7;               // staging 8-elem group

    // ---- early prefetch: flash tile 0 (latency hidden under phase 1) ----
    uint4 kpre = *(const uint4*)(K  + base + (size_t)srow * 64   + sg * 8);
    uint4 vpre = *(const uint4*)(VT + base + (size_t)srow * 2048 + sg * 8);

    // ---------------- Phase 1: Q tile (128 q x 64 d), pipelined ----------
    floatx4 qacc[4];
#pragma unroll
    for (int db = 0; db < 4; db++) qacc[db] = (floatx4){0.f,0.f,0.f,0.f};

    uint4 xpre[2], wpre;
#pragma unroll
    for (int p = 0; p < 2; p++)
        xpre[p] = load8bf(x, (size_t)(b_ * 2048 + q0 + srow + p * 64) * 1024
                              + sg * 8, f);
    wpre = load8bf(Wq, (size_t)(h * 64 + srow) * 1024 + sg * 8, f);

    for (int kb = 0; kb < 1024; kb += 64) {
        int buf = (kb >> 6) & 1;
        ushort* xs  = pool + buf * 8192;
        ushort* wsm = pool + 16384 + buf * 4096;
#pragma unroll
        for (int p = 0; p < 2; p++) {
            int row = srow + p * 64;
            *(uint4*)(&xs[row * 64 + ((sg ^ (row & 7)) << 3)]) = xpre[p];
        }
        *(uint4*)(&wsm[srow * 64 + ((sg ^ (srow & 7)) << 3)]) = wpre;
        __syncthreads();
        if (kb + 64 < 1024) {
#pragma unroll
            for (int p = 0; p < 2; p++)
                xpre[p] = load8bf(x, (size_t)(b_ * 2048 + q0 + srow + p * 64) * 1024
                                      + kb + 64 + sg * 8, f);
            wpre = load8bf(Wq, (size_t)(h * 64 + srow) * 1024 + kb + 64 + sg * 8, f);
        }
#pragma unroll
        for (int ks = 0; ks < 2; ks++) {
            int arow = wave * 16 + r15;
            short8 af = *(const short8*)(
                &xs[arow * 64 + (((ks * 4 + quad) ^ (arow & 7)) << 3)]);
#pragma unroll
            for (int db = 0; db < 4; db++) {
                int brow = db * 16 + r15;
                short8 bv = *(const short8*)(
                    &wsm[brow * 64 + (((ks * 4 + quad) ^ (brow & 7)) << 3)]);
                qacc[db] = __builtin_amdgcn_mfma_f32_16x16x32_bf16(
                    af, bv, qacc[db], 0, 0, 0);
            }
        }
    }

    // Qs overlays xs0 (last compute used xs1; own-wave rows only)
    ushort* Qs = pool;
    const float csc = 0.1803368801f;        // log2(e)/8
#pragma unroll
    for (int db = 0; db < 4; db++) {
        int d = db * 16 + r15;
        float bias = loadScalar(bq, h * 64 + d, f);
#pragma unroll
        for (int r = 0; r < 4; r++) {
            int q = wave * 16 + quad * 4 + r;
            Qs[q * 64 + (((d >> 3) ^ (q & 7)) << 3) + (d & 7)] =
                f2bf((qacc[db][r] + bias) * csc);
        }
    }
    short8 qf[2];
#pragma unroll
    for (int ks = 0; ks < 2; ks++) {
        int arow = wave * 16 + r15;
        qf[ks] = *(const short8*)(
            &Qs[arow * 64 + (((ks * 4 + quad) ^ (arow & 7)) << 3)]);
    }
    __syncthreads();   // qf loaded + phase-1 reads done before pool reuse

    // ---------------- Phase 2: flash loop (1 barrier / tile) -------------
    floatx4 oacc[4], lacc;
#pragma unroll
    for (int db = 0; db < 4; db++) oacc[db] = (floatx4){0.f,0.f,0.f,0.f};
    lacc = (floatx4){0.f,0.f,0.f,0.f};
    short8 ones;
#pragma unroll
    for (int j = 0; j < 8; j++) ones[j] = (short)0x3F80;   // bf16 1.0
    ushort* Ps = pool + 16384;
    const int e7 = (r15 & 7) << 1;          // P swizzle key ((q&7)<<1)

    for (int t0 = 0; t0 < 2048; t0 += 64) {
        int buf = (t0 >> 6) & 1;
        ushort* Ks = pool + buf * 4096;
        ushort* Vt = pool + 8192 + buf * 4096;
        *(uint4*)(&Ks[srow * 64 + ((sg ^ (srow & 7)) << 3)]) = kpre;
        *(uint4*)(&Vt[srow * 64 + ((sg ^ (srow & 7)) << 3)]) = vpre;
        __syncthreads();
        if (t0 < 1984) {
            kpre = *(const uint4*)(K  + base + (size_t)(t0 + 64 + srow) * 64
                                       + sg * 8);
            vpre = *(const uint4*)(VT + base + (size_t)srow * 2048
                                       + t0 + 64 + sg * 8);
        }

        // S^T = K Q^T : rows = keys, cols = this wave's 16 queries
        floatx4 s[4];
#pragma unroll
        for (int mb = 0; mb < 4; mb++) s[mb] = (floatx4){0.f,0.f,0.f,0.f};
#pragma unroll
        for (int ks = 0; ks < 2; ks++)
#pragma unroll
            for (int mb = 0; mb < 4; mb++) {
                int arow = mb * 16 + r15;
                short8 kf = *(const short8*)(
                    &Ks[arow * 64 + (((ks * 4 + quad) ^ (arow & 7)) << 3)]);
                s[mb] = __builtin_amdgcn_mfma_f32_16x16x32_bf16(
                    kf, qf[ks], s[mb], 0, 0, 0);
            }

        // P = 2^S, truncation-packed pairs -> own-wave b64 writes
#pragma unroll
        for (int mb = 0; mb < 4; mb++) {
            int q  = wave * 16 + r15;
            int tg = (mb * 4 + quad) ^ e7;
            uint b0 = __builtin_bit_cast(uint, __builtin_amdgcn_exp2f(s[mb][0]));
            uint b1 = __builtin_bit_cast(uint, __builtin_amdgcn_exp2f(s[mb][1]));
            uint b2 = __builtin_bit_cast(uint, __builtin_amdgcn_exp2f(s[mb][2]));
            uint b3 = __builtin_bit_cast(uint, __builtin_amdgcn_exp2f(s[mb][3]));
            uint2 pk;
            pk.x = (b1 & 0xFFFF0000u) | (b0 >> 16);
            pk.y = (b3 & 0xFFFF0000u) | (b2 >> 16);
            *(uint2*)(&Ps[q * 64 + tg * 4]) = pk;
        }

        // O += P V^T, l += P·1
#pragma unroll
        for (int ks2 = 0; ks2 < 2; ks2++) {
            int q   = wave * 16 + r15;
            int tg0 = (ks2 * 8 + quad * 2) ^ e7;
            short8 pf = *(const short8*)(&Ps[q * 64 + tg0 * 4]);
#pragma unroll
            for (int db = 0; db < 4; db++) {
                int brow = db * 16 + r15;
                short8 vf = *(const short8*)(
                    &Vt[brow * 64 + (((ks2 * 4 + quad) ^ (brow & 7)) << 3)]);
                oacc[db] = __builtin_amdgcn_mfma_f32_16x16x32_bf16(
                    pf, vf, oacc[db], 0, 0, 0);
            }
            lacc = __builtin_amdgcn_mfma_f32_16x16x32_bf16(
                pf, ones, lacc, 0, 0, 0);
        }
    }

    // ---- epilogue: O / l -> AO [B,S,1024] bf16 ----
    float inv[4];
#pragma unroll
    for (int r = 0; r < 4; r++) inv[r] = 1.f / lacc[r];
#pragma unroll
    for (int db = 0; db < 4; db++) {
        int d = db * 16 + r15;
#pragma unroll
        for (int r = 0; r < 4; r++) {
            int qi = q0 + wave * 16 + quad * 4 + r;
            AO[((size_t)(b_ * 2048 + qi) << 10) + h * 64 + d] =
                f2bf(oacc[db][r] * inv[r]);
        }
    }
}

__global__ void copy_u4(const uint4* __restrict__ src, uint4* __restrict__ dst) {
    size_t i = (size_t)blockIdx.x * 256 + threadIdx.x;
    dst[i] = src[i];
}

// ---------------------------------------------------------------------------
extern "C" void kernel_launch(void* const* d_in, const int* in_sizes, int n_in,
                              void* d_out, int out_size, void* d_ws, size_t ws_size,
                              hipStream_t stream)
{
    const void* x  = d_in[0];
    const void* Wq = d_in[1];
    const void* bq = d_in[2];
    const void* Wk = d_in[3];
    const void* bk = d_in[4];
    const void* Wv = d_in[5];
    const void* bv = d_in[6];
    const void* Wo = d_in[7];
    const void* bo = d_in[8];

    // ws: [flag, pad 256B][Kw 8MB][Vw(V^T) 8MB][AOw 8MB if ws_size allows]
    const size_t TEN = (size_t)2 * 16 * 2048 * 64;   // 4 Mi elements (8 MB)
    int*    flagp = (int*)d_ws;
    ushort* Kw    = (ushort*)((char*)d_ws + 256);
    ushort* Vw    = Kw + TEN;
    const bool big_ws = ws_size >= 3 * TEN * sizeof(ushort) + 256;
    ushort* AOw   = big_ws ? (Vw + TEN) : (ushort*)d_out;
    ushort* Oin   = big_ws ? AOw : Kw;    // O-proj input (Kw reused if small ws)

    detect_dtype<<<1, 256, 0, stream>>>((const ushort*)x, flagp);

    // K -> Kw [B,H,S,D] (pm=1) — grid (m,n) for same-XCD A-tile sharing
    gemm_bt<<<dim3(32, 16), dim3(512), 0, stream>>>(
        x, Wk, bk, Kw, /*pm=*/1, /*a_ext=*/1, /*out_ext=*/0, flagp);

    // V -> Vw [B,H,D,S] (pm=2); same grid shape -> x re-read hits warm L2
    gemm_bt<<<dim3(32, 16), dim3(512), 0, stream>>>(
        x, Wv, bv, Vw, /*pm=*/2, /*a_ext=*/1, /*out_ext=*/0, flagp);

    // fused Q-proj + attention -> AO (ws if it fits, else d_out staging)
    attn_fused<<<dim3(16, 32), dim3(512), 0, stream>>>(
        x, Wq, bq, Kw, Vw, AOw, flagp);

    // small-ws fallback: move AO out of d_out so O-proj is race-free
    if (!big_ws)
        copy_u4<<<dim3(2048), dim3(256), 0, stream>>>(
            (const uint4*)d_out, (uint4*)Oin);

    // O-projection -> final output (dtype per flag)
    gemm_bt<<<dim3(32, 16), dim3(512), 0, stream>>>(
        Oin, Wo, bo, d_out, /*pm=*/0, /*a_ext=*/0, /*out_ext=*/1, flagp);
}

// Round 14
// 239.508 us; speedup vs baseline: 1.6786x; 1.0109x over previous
//
#include <hip/hip_runtime.h>
#include <hip/hip_bf16.h>
#include <stdint.h>

using bf16 = __hip_bfloat16;
typedef __attribute__((ext_vector_type(8))) short   short8;
typedef __attribute__((ext_vector_type(4))) float   floatx4;

static __device__ __forceinline__ unsigned short f2bf(float f) {
    return __builtin_bit_cast(unsigned short, __float2bfloat16(f));
}

// 8 consecutive elements at element-offset e as packed bf16 (f=1: fp32 cvt).
static __device__ __forceinline__ uint4 load8bf(const void* p, size_t e, int f) {
    if (!f) return *(const uint4*)((const ushort*)p + e);
    const float* fp = (const float*)p + e;
    float4 a = *(const float4*)fp;
    float4 b = *(const float4*)(fp + 4);
    union { uint4 u; unsigned short s[8]; } r;
    r.s[0] = f2bf(a.x); r.s[1] = f2bf(a.y); r.s[2] = f2bf(a.z); r.s[3] = f2bf(a.w);
    r.s[4] = f2bf(b.x); r.s[5] = f2bf(b.y); r.s[6] = f2bf(b.z); r.s[7] = f2bf(b.w);
    return r.u;
}
static __device__ __forceinline__ float loadScalar(const void* p, int i, int f) {
    return f ? ((const float*)p)[i] : __bfloat162float(((const bf16*)p)[i]);
}

// ---------------------------------------------------------------------------
__global__ void detect_dtype(const ushort* __restrict__ x, int* __restrict__ flag) {
    __shared__ int cnt;
    if (threadIdx.x == 0) cnt = 0;
    __syncthreads();
    unsigned short u = x[threadIdx.x * 2];
    int e = (u >> 7) & 0xFF;
    int bad = (e > 133 || e < 94) ? 1 : 0;
    atomicAdd(&cnt, bad);
    __syncthreads();
    if (threadIdx.x == 0) *flag = (cnt > 64) ? 1 : 0;
}

// ---------------------------------------------------------------------------
// NT GEMM: 512 thr / 8 waves, 128m x 64n tile, BK=64, 2-deep register
// prefetch + double-buffered XOR-swizzled LDS, ONE barrier per iter.
// Grid: x = m-tile (same-A blocks stride 32 == 0 mod 8 -> one XCD's L2),
// y = n-tile, z selects (W, bias, Out, pm) so K+V projections share one
// dispatch (z-plane offset 512 == 0 mod 8 keeps the XCD mapping).
// R11 lesson kept: `#pragma unroll 2` (dynamic prefetch-slot index spills
// to HBM-backed scratch); launch_bounds (512,2).
// pm: 0 row-major [M,1024]; 1 scatter bf16 [B,H,S,D];
//     2 V^T [B,H,D,S] via LDS transpose, full-line stores (s-off m0&2047).
// ---------------------------------------------------------------------------
__global__ __launch_bounds__(512, 2)
void gemm_bt(const void* __restrict__ A,
             const void* __restrict__ Wa, const void* __restrict__ Wb,
             const void* __restrict__ Ba, const void* __restrict__ Bb,
             void* __restrict__ Oa, void* __restrict__ Ob_,
             int pa, int pb, int a_ext, int out_ext,
             const int* __restrict__ flagp)
{
    __shared__ ushort pool[24576];   // 48 KB: As dbuf 2x16KB, Ws dbuf 2x8KB

    const int f  = *flagp;
    const int fA = a_ext ? f : 0;
    const int z  = blockIdx.z;
    const void* W   = z ? Wb : Wa;
    const void* Bi  = z ? Bb : Ba;
    void*       Out = z ? Ob_ : Oa;
    const int   pm  = z ? pb : pa;

    const int m0 = blockIdx.x * 128;        // x = m-tile (32 values)
    const int n0 = blockIdx.y * 64;         // y = n-tile (16 values)
    const int tid  = threadIdx.x;
    const int lane = tid & 63;
    const int wave = tid >> 6;              // 0..7, owns m-rows wave*16..+15
    const int r15  = lane & 15;
    const int quad = lane >> 4;

    const int srow = tid >> 3;              // staging row 0..63
    const int sg   = tid & 7;               // staging 8-elem group

    floatx4 acc[4];
#pragma unroll
    for (int db = 0; db < 4; db++) acc[db] = (floatx4){0.f, 0.f, 0.f, 0.f};

    // 2-deep prefetch: slot s holds data for iter with (it&1)==s
    uint4 apre[2][2], wpre[2];
#pragma unroll
    for (int s = 0; s < 2; s++) {
#pragma unroll
        for (int p = 0; p < 2; p++)
            apre[s][p] = load8bf(A, (size_t)(m0 + srow + p * 64) * 1024
                                     + s * 64 + sg * 8, fA);
        wpre[s] = load8bf(W, (size_t)(n0 + srow) * 1024 + s * 64 + sg * 8, f);
    }

#pragma unroll 2
    for (int kb = 0; kb < 1024; kb += 64) {
        const int sl = (kb >> 6) & 1;       // compile-time under unroll-2
        ushort* xs  = pool + sl * 8192;
        ushort* wsm = pool + 16384 + sl * 4096;
#pragma unroll
        for (int p = 0; p < 2; p++) {
            int row = srow + p * 64;
            *(uint4*)(&xs[row * 64 + ((sg ^ (row & 7)) << 3)]) = apre[sl][p];
        }
        *(uint4*)(&wsm[srow * 64 + ((sg ^ (srow & 7)) << 3)]) = wpre[sl];
        __syncthreads();
        if (kb + 128 < 1024) {
#pragma unroll
            for (int p = 0; p < 2; p++)
                apre[sl][p] = load8bf(A, (size_t)(m0 + srow + p * 64) * 1024
                                          + kb + 128 + sg * 8, fA);
            wpre[sl] = load8bf(W, (size_t)(n0 + srow) * 1024 + kb + 128 + sg * 8, f);
        }
#pragma unroll
        for (int ks = 0; ks < 2; ks++) {
            int arow = wave * 16 + r15;
            short8 af = *(const short8*)(
                &xs[arow * 64 + (((ks * 4 + quad) ^ (arow & 7)) << 3)]);
#pragma unroll
            for (int db = 0; db < 4; db++) {
                int brow = db * 16 + r15;
                short8 bv = *(const short8*)(
                    &wsm[brow * 64 + (((ks * 4 + quad) ^ (brow & 7)) << 3)]);
                acc[db] = __builtin_amdgcn_mfma_f32_16x16x32_bf16(
                    af, bv, acc[db], 0, 0, 0);
            }
        }
    }

    // C/D layout: col = lane&15, row = quad*4 + r (m89/m91)
    if (pm == 2) {
        // ---- V^T epilogue: acc -> LDS T[64 d][128 s] (swizzled) -> global ----
        __syncthreads();                    // all K-loop LDS reads done
#pragma unroll
        for (int db = 0; db < 4; db++) {
            int d = db * 16 + r15;
            float bias = loadScalar(Bi, n0 + d, f);
            int s4 = wave * 16 + quad * 4;  // s local, 4-aligned
            union { uint2 u; ushort us[4]; } pk;
#pragma unroll
            for (int r = 0; r < 4; r++) pk.us[r] = f2bf(acc[db][r] + bias);
            *(uint2*)(&pool[d * 128 + (((s4 >> 3) ^ (d & 15)) << 3) + (s4 & 7)])
                = pk.u;
        }
        __syncthreads();
        const int b_  = m0 >> 11;
        const int h   = n0 >> 6;
        const int sl0 = m0 & 2047;          // s-offset within batch
#pragma unroll
        for (int rr = 0; rr < 2; rr++) {
            int idx = rr * 512 + tid;       // 0..1023
            int d = idx >> 4, sgrp = idx & 15;
            uint4 v = *(const uint4*)(&pool[d * 128 + ((sgrp ^ (d & 15)) << 3)]);
            *(uint4*)((ushort*)Out +
                      ((size_t)((b_ * 16 + h) * 64 + d) << 11) + sl0 + sgrp * 8) = v;
        }
        return;
    }

#pragma unroll
    for (int db = 0; db < 4; db++) {
        int col = n0 + db * 16 + r15;
        float bias = loadScalar(Bi, col, f);
#pragma unroll
        for (int r = 0; r < 4; r++) {
            int row = m0 + wave * 16 + quad * 4 + r;
            float v = acc[db][r] + bias;
            if (pm == 1) {
                int h = col >> 6, d = col & 63;
                int b_ = row >> 11, s = row & 2047;
                ((ushort*)Out)[(((size_t)(b_ * 16 + h) * 2048 + s) << 6) + d]
                    = f2bf(v);
            } else if (out_ext && f) {
                ((float*)Out)[(size_t)row * 1024 + col] = v;
            } else {
                ((ushort*)Out)[(size_t)row * 1024 + col] = f2bf(v);
            }
        }
    }
}

// ---------------------------------------------------------------------------
// Fused Q-projection + flash attention (R7/R10 structure — measured ~84 µs).
// R14 change: grid is (x = bh, y = q-tile).  Same-bh blocks (sharing 512 KB
// of K+V^T, read 16x) have linear IDs stride 32 == 0 mod 8 -> one XCD's L2
// (4 bh per XCD = 2 MB working set).  Kernel body unchanged.
// ---------------------------------------------------------------------------
__global__ __launch_bounds__(512, 4)
void attn_fused(const void* __restrict__ x, const void* __restrict__ Wq,
                const void* __restrict__ bq,
                const ushort* __restrict__ K, const ushort* __restrict__ VT,
                ushort* __restrict__ AO, const int* __restrict__ flagp)
{
    __shared__ ushort pool[24576];          // 48 KB

    const int f   = *flagp;
    const int bh  = blockIdx.x;             // x = bh (32 values)
    const int h   = bh & 15, b_ = bh >> 4;
    const int q0  = blockIdx.y * 128;       // y = q-tile (16 values)
    const int tid  = threadIdx.x;
    const int lane = tid & 63;
    const int wave = tid >> 6;              // 0..7, owns q rows wave*16..+15
    const int r15  = lane & 15;
    const int quad = lane >> 4;
    const size_t base = (size_t)bh << 17;

    const int srow = tid >> 3;              // staging row 0..63
    const int sg   = tid & 7;               // staging 8-elem group

    // ---- early prefetch: flash tile 0 (latency hidden under phase 1) ----
    uint4 kpre = *(const uint4*)(K  + base + (size_t)srow * 64   + sg * 8);
    uint4 vpre = *(const uint4*)(VT + base + (size_t)srow * 2048 + sg * 8);

    // ---------------- Phase 1: Q tile (128 q x 64 d), pipelined ----------
    floatx4 qacc[4];
#pragma unroll
    for (int db = 0; db < 4; db++) qacc[db] = (floatx4){0.f,0.f,0.f,0.f};

    uint4 xpre[2], wpre;
#pragma unroll
    for (int p = 0; p < 2; p++)
        xpre[p] = load8bf(x, (size_t)(b_ * 2048 + q0 + srow + p * 64) * 1024
                              + sg * 8, f);
    wpre = load8bf(Wq, (size_t)(h * 64 + srow) * 1024 + sg * 8, f);

    for (int kb = 0; kb < 1024; kb += 64) {
        int buf = (kb >> 6) & 1;
        ushort* xs  = pool + buf * 8192;
        ushort* wsm = pool + 16384 + buf * 4096;
#pragma unroll
        for (int p = 0; p < 2; p++) {
            int row = srow + p * 64;
            *(uint4*)(&xs[row * 64 + ((sg ^ (row & 7)) << 3)]) = xpre[p];
        }
        *(uint4*)(&wsm[srow * 64 + ((sg ^ (srow & 7)) << 3)]) = wpre;
        __syncthreads();
        if (kb + 64 < 1024) {
#pragma unroll
            for (int p = 0; p < 2; p++)
                xpre[p] = load8bf(x, (size_t)(b_ * 2048 + q0 + srow + p * 64) * 1024
                                      + kb + 64 + sg * 8, f);
            wpre = load8bf(Wq, (size_t)(h * 64 + srow) * 1024 + kb + 64 + sg * 8, f);
        }
#pragma unroll
        for (int ks = 0; ks < 2; ks++) {
            int arow = wave * 16 + r15;
            short8 af = *(const short8*)(
                &xs[arow * 64 + (((ks * 4 + quad) ^ (arow & 7)) << 3)]);
#pragma unroll
            for (int db = 0; db < 4; db++) {
                int brow = db * 16 + r15;
                short8 bv = *(const short8*)(
                    &wsm[brow * 64 + (((ks * 4 + quad) ^ (brow & 7)) << 3)]);
                qacc[db] = __builtin_amdgcn_mfma_f32_16x16x32_bf16(
                    af, bv, qacc[db], 0, 0, 0);
            }
        }
    }

    // Qs overlays xs0 (last compute used xs1; own-wave rows only)
    ushort* Qs = pool;
    const float csc = 0.1803368801f;        // log2(e)/8
#pragma unroll
    for (int db = 0; db < 4; db++) {
        int d = db * 16 + r15;
        float bias = loadScalar(bq, h * 64 + d, f);
#pragma unroll
        for (int r = 0; r < 4; r++) {
            int q = wave * 16 + quad * 4 + r;
            Qs[q * 64 + (((d >> 3) ^ (q & 7)) << 3) + (d & 7)] =
                f2bf((qacc[db][r] + bias) * csc);
        }
    }
    short8 qf[2];
#pragma unroll
    for (int ks = 0; ks < 2; ks++) {
        int arow = wave * 16 + r15;
        qf[ks] = *(const short8*)(
            &Qs[arow * 64 + (((ks * 4 + quad) ^ (arow & 7)) << 3)]);
    }
    __syncthreads();   // qf loaded + phase-1 reads done before pool reuse

    // ---------------- Phase 2: flash loop (1 barrier / tile) -------------
    floatx4 oacc[4], lacc;
#pragma unroll
    for (int db = 0; db < 4; db++) oacc[db] = (floatx4){0.f,0.f,0.f,0.f};
    lacc = (floatx4){0.f,0.f,0.f,0.f};
    short8 ones;
#pragma unroll
    for (int j = 0; j < 8; j++) ones[j] = (short)0x3F80;   // bf16 1.0
    ushort* Ps = pool + 16384;
    const int e7 = (r15 & 7) << 1;          // P swizzle key ((q&7)<<1)

    for (int t0 = 0; t0 < 2048; t0 += 64) {
        int buf = (t0 >> 6) & 1;
        ushort* Ks = pool + buf * 4096;
        ushort* Vt = pool + 8192 + buf * 4096;
        *(uint4*)(&Ks[srow * 64 + ((sg ^ (srow & 7)) << 3)]) = kpre;
        *(uint4*)(&Vt[srow * 64 + ((sg ^ (srow & 7)) << 3)]) = vpre;
        __syncthreads();
        if (t0 < 1984) {
            kpre = *(const uint4*)(K  + base + (size_t)(t0 + 64 + srow) * 64
                                       + sg * 8);
            vpre = *(const uint4*)(VT + base + (size_t)srow * 2048
                                       + t0 + 64 + sg * 8);
        }

        // S^T = K Q^T : rows = keys, cols = this wave's 16 queries
        floatx4 s[4];
#pragma unroll
        for (int mb = 0; mb < 4; mb++) s[mb] = (floatx4){0.f,0.f,0.f,0.f};
#pragma unroll
        for (int ks = 0; ks < 2; ks++)
#pragma unroll
            for (int mb = 0; mb < 4; mb++) {
                int arow = mb * 16 + r15;
                short8 kf = *(const short8*)(
                    &Ks[arow * 64 + (((ks * 4 + quad) ^ (arow & 7)) << 3)]);
                s[mb] = __builtin_amdgcn_mfma_f32_16x16x32_bf16(
                    kf, qf[ks], s[mb], 0, 0, 0);
            }

        // P = 2^S, truncation-packed pairs -> own-wave b64 writes
#pragma unroll
        for (int mb = 0; mb < 4; mb++) {
            int q  = wave * 16 + r15;
            int tg = (mb * 4 + quad) ^ e7;
            uint b0 = __builtin_bit_cast(uint, __builtin_amdgcn_exp2f(s[mb][0]));
            uint b1 = __builtin_bit_cast(uint, __builtin_amdgcn_exp2f(s[mb][1]));
            uint b2 = __builtin_bit_cast(uint, __builtin_amdgcn_exp2f(s[mb][2]));
            uint b3 = __builtin_bit_cast(uint, __builtin_amdgcn_exp2f(s[mb][3]));
            uint2 pk;
            pk.x = (b1 & 0xFFFF0000u) | (b0 >> 16);
            pk.y = (b3 & 0xFFFF0000u) | (b2 >> 16);
            *(uint2*)(&Ps[q * 64 + tg * 4]) = pk;
        }

        // O += P V^T, l += P·1
#pragma unroll
        for (int ks2 = 0; ks2 < 2; ks2++) {
            int q   = wave * 16 + r15;
            int tg0 = (ks2 * 8 + quad * 2) ^ e7;
            short8 pf = *(const short8*)(&Ps[q * 64 + tg0 * 4]);
#pragma unroll
            for (int db = 0; db < 4; db++) {
                int brow = db * 16 + r15;
                short8 vf = *(const short8*)(
                    &Vt[brow * 64 + (((ks2 * 4 + quad) ^ (brow & 7)) << 3)]);
                oacc[db] = __builtin_amdgcn_mfma_f32_16x16x32_bf16(
                    pf, vf, oacc[db], 0, 0, 0);
            }
            lacc = __builtin_amdgcn_mfma_f32_16x16x32_bf16(
                pf, ones, lacc, 0, 0, 0);
        }
    }

    // ---- epilogue: O / l -> AO [B,S,1024] bf16 ----
    float inv[4];
#pragma unroll
    for (int r = 0; r < 4; r++) inv[r] = 1.f / lacc[r];
#pragma unroll
    for (int db = 0; db < 4; db++) {
        int d = db * 16 + r15;
#pragma unroll
        for (int r = 0; r < 4; r++) {
            int qi = q0 + wave * 16 + quad * 4 + r;
            AO[((size_t)(b_ * 2048 + qi) << 10) + h * 64 + d] =
                f2bf(oacc[db][r] * inv[r]);
        }
    }
}

__global__ void copy_u4(const uint4* __restrict__ src, uint4* __restrict__ dst) {
    size_t i = (size_t)blockIdx.x * 256 + threadIdx.x;
    dst[i] = src[i];
}

// ---------------------------------------------------------------------------
extern "C" void kernel_launch(void* const* d_in, const int* in_sizes, int n_in,
                              void* d_out, int out_size, void* d_ws, size_t ws_size,
                              hipStream_t stream)
{
    const void* x  = d_in[0];
    const void* Wq = d_in[1];
    const void* bq = d_in[2];
    const void* Wk = d_in[3];
    const void* bk = d_in[4];
    const void* Wv = d_in[5];
    const void* bv = d_in[6];
    const void* Wo = d_in[7];
    const void* bo = d_in[8];

    // ws: [flag, pad 256B][Kw 8MB][Vw(V^T) 8MB][AOw 8MB if ws_size allows]
    const size_t TEN = (size_t)2 * 16 * 2048 * 64;   // 4 Mi elements (8 MB)
    int*    flagp = (int*)d_ws;
    ushort* Kw    = (ushort*)((char*)d_ws + 256);
    ushort* Vw    = Kw + TEN;
    const bool big_ws = ws_size >= 3 * TEN * sizeof(ushort) + 256;
    ushort* AOw   = big_ws ? (Vw + TEN) : (ushort*)d_out;
    ushort* Oin   = big_ws ? AOw : Kw;    // O-proj input (Kw reused if small ws)

    detect_dtype<<<1, 256, 0, stream>>>((const ushort*)x, flagp);

    // K -> Kw [B,H,S,D] (pm=1) and V -> Vw [B,H,D,S] (pm=2) in ONE dispatch
    gemm_bt<<<dim3(32, 16, 2), dim3(512), 0, stream>>>(
        x, Wk, Wv, bk, bv, Kw, Vw, /*pa=*/1, /*pb=*/2, /*a_ext=*/1,
        /*out_ext=*/0, flagp);

    // fused Q-proj + attention -> AO (grid bh-major for XCD K/V^T locality)
    attn_fused<<<dim3(32, 16), dim3(512), 0, stream>>>(
        x, Wq, bq, Kw, Vw, AOw, flagp);

    // small-ws fallback: move AO out of d_out so O-proj is race-free
    if (!big_ws)
        copy_u4<<<dim3(2048), dim3(256), 0, stream>>>(
            (const uint4*)d_out, (uint4*)Oin);

    // O-projection -> final output (dtype per flag)
    gemm_bt<<<dim3(32, 16, 1), dim3(512), 0, stream>>>(
        Oin, Wo, Wo, bo, bo, d_out, d_out, /*pa=*/0, /*pb=*/0, /*a_ext=*/0,
        /*out_ext=*/1, flagp);
}

// Round 15
// 227.007 us; speedup vs baseline: 1.7710x; 1.0551x over previous
//
#include <hip/hip_runtime.h>
#include <hip/hip_bf16.h>
#include <stdint.h>

using bf16 = __hip_bfloat16;
typedef __attribute__((ext_vector_type(8))) short   short8;
typedef __attribute__((ext_vector_type(4))) float   floatx4;

static __device__ __forceinline__ unsigned short f2bf(float f) {
    return __builtin_bit_cast(unsigned short, __float2bfloat16(f));
}

// 8 consecutive elements at element-offset e as packed bf16 (f=1: fp32 cvt).
static __device__ __forceinline__ uint4 load8bf(const void* p, size_t e, int f) {
    if (!f) return *(const uint4*)((const ushort*)p + e);
    const float* fp = (const float*)p + e;
    float4 a = *(const float4*)fp;
    float4 b = *(const float4*)(fp + 4);
    union { uint4 u; unsigned short s[8]; } r;
    r.s[0] = f2bf(a.x); r.s[1] = f2bf(a.y); r.s[2] = f2bf(a.z); r.s[3] = f2bf(a.w);
    r.s[4] = f2bf(b.x); r.s[5] = f2bf(b.y); r.s[6] = f2bf(b.z); r.s[7] = f2bf(b.w);
    return r.u;
}
static __device__ __forceinline__ float loadScalar(const void* p, int i, int f) {
    return f ? ((const float*)p)[i] : __bfloat162float(((const bf16*)p)[i]);
}

// ---------------------------------------------------------------------------
__global__ void detect_dtype(const ushort* __restrict__ x, int* __restrict__ flag) {
    __shared__ int cnt;
    if (threadIdx.x == 0) cnt = 0;
    __syncthreads();
    unsigned short u = x[threadIdx.x * 2];
    int e = (u >> 7) & 0xFF;
    int bad = (e > 133 || e < 94) ? 1 : 0;
    atomicAdd(&cnt, bad);
    __syncthreads();
    if (threadIdx.x == 0) *flag = (cnt > 64) ? 1 : 0;
}

// ---------------------------------------------------------------------------
// NT GEMM: 512 thr / 8 waves, 128m x 64n tile, BK=64, 1-deep register
// prefetch, SINGLE-buffered LDS (24 KB: As 16 KB + Ws 8 KB), 2 barriers/iter.
// R15 change: 48->24 KB LDS raises the LDS residency cap 3->6 blocks/CU;
// with ~50-60 VGPRs at launch_bounds(512,4) (VGPR cap 128 — no R11 spill
// risk) actual residency is 4 blocks/CU, so the merged KV dispatch (1024
// blocks) runs in ONE round instead of 1.33, and 4 independent blocks/CU
// overlap each other's barrier drains.
// Grid: x = m-tile (same-A blocks stride 32 == 0 mod 8 -> one XCD's L2),
// y = n-tile, z selects (W, bias, Out, pm).
// pm: 0 row-major [M,1024]; 1 scatter bf16 [B,H,S,D];
//     2 V^T [B,H,D,S] via LDS transpose, full-line stores (s-off m0&2047).
// ---------------------------------------------------------------------------
__global__ __launch_bounds__(512, 4)
void gemm_bt(const void* __restrict__ A,
             const void* __restrict__ Wa, const void* __restrict__ Wb,
             const void* __restrict__ Ba, const void* __restrict__ Bb,
             void* __restrict__ Oa, void* __restrict__ Ob_,
             int pa, int pb, int a_ext, int out_ext,
             const int* __restrict__ flagp)
{
    __shared__ ushort pool[12288];   // 24 KB: As[128x64] @0, Ws[64x64] @8192

    const int f  = *flagp;
    const int fA = a_ext ? f : 0;
    const int z  = blockIdx.z;
    const void* W   = z ? Wb : Wa;
    const void* Bi  = z ? Bb : Ba;
    void*       Out = z ? Ob_ : Oa;
    const int   pm  = z ? pb : pa;

    const int m0 = blockIdx.x * 128;        // x = m-tile (32 values)
    const int n0 = blockIdx.y * 64;         // y = n-tile (16 values)
    const int tid  = threadIdx.x;
    const int lane = tid & 63;
    const int wave = tid >> 6;              // 0..7, owns m-rows wave*16..+15
    const int r15  = lane & 15;
    const int quad = lane >> 4;

    const int srow = tid >> 3;              // staging row 0..63
    const int sg   = tid & 7;               // staging 8-elem group

    ushort* xs  = pool;                     // A tile
    ushort* wsm = pool + 8192;              // W tile

    floatx4 acc[4];
#pragma unroll
    for (int db = 0; db < 4; db++) acc[db] = (floatx4){0.f, 0.f, 0.f, 0.f};

    // 1-deep prefetch (iter 0)
    uint4 apre[2], wpre;
#pragma unroll
    for (int p = 0; p < 2; p++)
        apre[p] = load8bf(A, (size_t)(m0 + srow + p * 64) * 1024 + sg * 8, fA);
    wpre = load8bf(W, (size_t)(n0 + srow) * 1024 + sg * 8, f);

    for (int kb = 0; kb < 1024; kb += 64) {
#pragma unroll
        for (int p = 0; p < 2; p++) {
            int row = srow + p * 64;
            *(uint4*)(&xs[row * 64 + ((sg ^ (row & 7)) << 3)]) = apre[p];
        }
        *(uint4*)(&wsm[srow * 64 + ((sg ^ (srow & 7)) << 3)]) = wpre;
        __syncthreads();
        if (kb + 64 < 1024) {
#pragma unroll
            for (int p = 0; p < 2; p++)
                apre[p] = load8bf(A, (size_t)(m0 + srow + p * 64) * 1024
                                      + kb + 64 + sg * 8, fA);
            wpre = load8bf(W, (size_t)(n0 + srow) * 1024 + kb + 64 + sg * 8, f);
        }
#pragma unroll
        for (int ks = 0; ks < 2; ks++) {
            int arow = wave * 16 + r15;
            short8 af = *(const short8*)(
                &xs[arow * 64 + (((ks * 4 + quad) ^ (arow & 7)) << 3)]);
#pragma unroll
            for (int db = 0; db < 4; db++) {
                int brow = db * 16 + r15;
                short8 bv = *(const short8*)(
                    &wsm[brow * 64 + (((ks * 4 + quad) ^ (brow & 7)) << 3)]);
                acc[db] = __builtin_amdgcn_mfma_f32_16x16x32_bf16(
                    af, bv, acc[db], 0, 0, 0);
            }
        }
        __syncthreads();   // compute reads done before next iteration's writes
    }

    // C/D layout: col = lane&15, row = quad*4 + r (m89/m91)
    if (pm == 2) {
        // ---- V^T epilogue: acc -> LDS T[64 d][128 s] (swizzled) -> global ----
#pragma unroll
        for (int db = 0; db < 4; db++) {
            int d = db * 16 + r15;
            float bias = loadScalar(Bi, n0 + d, f);
            int s4 = wave * 16 + quad * 4;  // s local, 4-aligned
            union { uint2 u; ushort us[4]; } pk;
#pragma unroll
            for (int r = 0; r < 4; r++) pk.us[r] = f2bf(acc[db][r] + bias);
            *(uint2*)(&pool[d * 128 + (((s4 >> 3) ^ (d & 15)) << 3) + (s4 & 7)])
                = pk.u;
        }
        __syncthreads();
        const int b_  = m0 >> 11;
        const int h   = n0 >> 6;
        const int sl0 = m0 & 2047;          // s-offset within batch
#pragma unroll
        for (int rr = 0; rr < 2; rr++) {
            int idx = rr * 512 + tid;       // 0..1023
            int d = idx >> 4, sgrp = idx & 15;
            uint4 v = *(const uint4*)(&pool[d * 128 + ((sgrp ^ (d & 15)) << 3)]);
            *(uint4*)((ushort*)Out +
                      ((size_t)((b_ * 16 + h) * 64 + d) << 11) + sl0 + sgrp * 8) = v;
        }
        return;
    }

#pragma unroll
    for (int db = 0; db < 4; db++) {
        int col = n0 + db * 16 + r15;
        float bias = loadScalar(Bi, col, f);
#pragma unroll
        for (int r = 0; r < 4; r++) {
            int row = m0 + wave * 16 + quad * 4 + r;
            float v = acc[db][r] + bias;
            if (pm == 1) {
                int h = col >> 6, d = col & 63;
                int b_ = row >> 11, s = row & 2047;
                ((ushort*)Out)[(((size_t)(b_ * 16 + h) * 2048 + s) << 6) + d]
                    = f2bf(v);
            } else if (out_ext && f) {
                ((float*)Out)[(size_t)row * 1024 + col] = v;
            } else {
                ((ushort*)Out)[(size_t)row * 1024 + col] = f2bf(v);
            }
        }
    }
}

// ---------------------------------------------------------------------------
// Fused Q-projection + flash attention (R7/R10 structure — measured ~86 µs,
// UNCHANGED).  512 thr / 8 waves, 128 q/block, dbuf LDS, reg prefetch,
// ONE barrier per 64-key tile.  Grid (x=bh, y=q-tile) for XCD K/V^T locality
// (R14: FETCH 90->76 MB).  Fixed-max softmax (log2(e)/8 in Q), l via
// ones-MFMA, P truncation-packed through own-wave LDS rows.
// ---------------------------------------------------------------------------
__global__ __launch_bounds__(512, 4)
void attn_fused(const void* __restrict__ x, const void* __restrict__ Wq,
                const void* __restrict__ bq,
                const ushort* __restrict__ K, const ushort* __restrict__ VT,
                ushort* __restrict__ AO, const int* __restrict__ flagp)
{
    __shared__ ushort pool[24576];          // 48 KB

    const int f   = *flagp;
    const int bh  = blockIdx.x;             // x = bh (32 values)
    const int h   = bh & 15, b_ = bh >> 4;
    const int q0  = blockIdx.y * 128;       // y = q-tile (16 values)
    const int tid  = threadIdx.x;
    const int lane = tid & 63;
    const int wave = tid >> 6;              // 0..7, owns q rows wave*16..+15
    const int r15  = lane & 15;
    const int quad = lane >> 4;
    const size_t base = (size_t)bh << 17;

    const int srow = tid >> 3;              // staging row 0..63
    const int sg   = tid & 7;               // staging 8-elem group

    // ---- early prefetch: flash tile 0 (latency hidden under phase 1) ----
    uint4 kpre = *(const uint4*)(K  + base + (size_t)srow * 64   + sg * 8);
    uint4 vpre = *(const uint4*)(VT + base + (size_t)srow * 2048 + sg * 8);

    // ---------------- Phase 1: Q tile (128 q x 64 d), pipelined ----------
    floatx4 qacc[4];
#pragma unroll
    for (int db = 0; db < 4; db++) qacc[db] = (floatx4){0.f,0.f,0.f,0.f};

    uint4 xpre[2], wpre;
#pragma unroll
    for (int p = 0; p < 2; p++)
        xpre[p] = load8bf(x, (size_t)(b_ * 2048 + q0 + srow + p * 64) * 1024
                              + sg * 8, f);
    wpre = load8bf(Wq, (size_t)(h * 64 + srow) * 1024 + sg * 8, f);

    for (int kb = 0; kb < 1024; kb += 64) {
        int buf = (kb >> 6) & 1;
        ushort* xs  = pool + buf * 8192;
        ushort* wsm = pool + 16384 + buf * 4096;
#pragma unroll
        for (int p = 0; p < 2; p++) {
            int row = srow + p * 64;
            *(uint4*)(&xs[row * 64 + ((sg ^ (row & 7)) << 3)]) = xpre[p];
        }
        *(uint4*)(&wsm[srow * 64 + ((sg ^ (srow & 7)) << 3)]) = wpre;
        __syncthreads();
        if (kb + 64 < 1024) {
#pragma unroll
            for (int p = 0; p < 2; p++)
                xpre[p] = load8bf(x, (size_t)(b_ * 2048 + q0 + srow + p * 64) * 1024
                                      + kb + 64 + sg * 8, f);
            wpre = load8bf(Wq, (size_t)(h * 64 + srow) * 1024 + kb + 64 + sg * 8, f);
        }
#pragma unroll
        for (int ks = 0; ks < 2; ks++) {
            int arow = wave * 16 + r15;
            short8 af = *(const short8*)(
                &xs[arow * 64 + (((ks * 4 + quad) ^ (arow & 7)) << 3)]);
#pragma unroll
            for (int db = 0; db < 4; db++) {
                int brow = db * 16 + r15;
                short8 bv = *(const short8*)(
                    &wsm[brow * 64 + (((ks * 4 + quad) ^ (brow & 7)) << 3)]);
                qacc[db] = __builtin_amdgcn_mfma_f32_16x16x32_bf16(
                    af, bv, qacc[db], 0, 0, 0);
            }
        }
    }

    // Qs overlays xs0 (last compute used xs1; own-wave rows only)
    ushort* Qs = pool;
    const float csc = 0.1803368801f;        // log2(e)/8
#pragma unroll
    for (int db = 0; db < 4; db++) {
        int d = db * 16 + r15;
        float bias = loadScalar(bq, h * 64 + d, f);
#pragma unroll
        for (int r = 0; r < 4; r++) {
            int q = wave * 16 + quad * 4 + r;
            Qs[q * 64 + (((d >> 3) ^ (q & 7)) << 3) + (d & 7)] =
                f2bf((qacc[db][r] + bias) * csc);
        }
    }
    short8 qf[2];
#pragma unroll
    for (int ks = 0; ks < 2; ks++) {
        int arow = wave * 16 + r15;
        qf[ks] = *(const short8*)(
            &Qs[arow * 64 + (((ks * 4 + quad) ^ (arow & 7)) << 3)]);
    }
    __syncthreads();   // qf loaded + phase-1 reads done before pool reuse

    // ---------------- Phase 2: flash loop (1 barrier / tile) -------------
    floatx4 oacc[4], lacc;
#pragma unroll
    for (int db = 0; db < 4; db++) oacc[db] = (floatx4){0.f,0.f,0.f,0.f};
    lacc = (floatx4){0.f,0.f,0.f,0.f};
    short8 ones;
#pragma unroll
    for (int j = 0; j < 8; j++) ones[j] = (short)0x3F80;   // bf16 1.0
    ushort* Ps = pool + 16384;
    const int e7 = (r15 & 7) << 1;          // P swizzle key ((q&7)<<1)

    for (int t0 = 0; t0 < 2048; t0 += 64) {
        int buf = (t0 >> 6) & 1;
        ushort* Ks = pool + buf * 4096;
        ushort* Vt = pool + 8192 + buf * 4096;
        *(uint4*)(&Ks[srow * 64 + ((sg ^ (srow & 7)) << 3)]) = kpre;
        *(uint4*)(&Vt[srow * 64 + ((sg ^ (srow & 7)) << 3)]) = vpre;
        __syncthreads();
        if (t0 < 1984) {
            kpre = *(const uint4*)(K  + base + (size_t)(t0 + 64 + srow) * 64
                                       + sg * 8);
            vpre = *(const uint4*)(VT + base + (size_t)srow * 2048
                                       + t0 + 64 + sg * 8);
        }

        // S^T = K Q^T : rows = keys, cols = this wave's 16 queries
        floatx4 s[4];
#pragma unroll
        for (int mb = 0; mb < 4; mb++) s[mb] = (floatx4){0.f,0.f,0.f,0.f};
#pragma unroll
        for (int ks = 0; ks < 2; ks++)
#pragma unroll
            for (int mb = 0; mb < 4; mb++) {
                int arow = mb * 16 + r15;
                short8 kf = *(const short8*)(
                    &Ks[arow * 64 + (((ks * 4 + quad) ^ (arow & 7)) << 3)]);
                s[mb] = __builtin_amdgcn_mfma_f32_16x16x32_bf16(
                    kf, qf[ks], s[mb], 0, 0, 0);
            }

        // P = 2^S, truncation-packed pairs -> own-wave b64 writes
#pragma unroll
        for (int mb = 0; mb < 4; mb++) {
            int q  = wave * 16 + r15;
            int tg = (mb * 4 + quad) ^ e7;
            uint b0 = __builtin_bit_cast(uint, __builtin_amdgcn_exp2f(s[mb][0]));
            uint b1 = __builtin_bit_cast(uint, __builtin_amdgcn_exp2f(s[mb][1]));
            uint b2 = __builtin_bit_cast(uint, __builtin_amdgcn_exp2f(s[mb][2]));
            uint b3 = __builtin_bit_cast(uint, __builtin_amdgcn_exp2f(s[mb][3]));
            uint2 pk;
            pk.x = (b1 & 0xFFFF0000u) | (b0 >> 16);
            pk.y = (b3 & 0xFFFF0000u) | (b2 >> 16);
            *(uint2*)(&Ps[q * 64 + tg * 4]) = pk;
        }

        // O += P V^T, l += P·1
#pragma unroll
        for (int ks2 = 0; ks2 < 2; ks2++) {
            int q   = wave * 16 + r15;
            int tg0 = (ks2 * 8 + quad * 2) ^ e7;
            short8 pf = *(const short8*)(&Ps[q * 64 + tg0 * 4]);
#pragma unroll
            for (int db = 0; db < 4; db++) {
                int brow = db * 16 + r15;
                short8 vf = *(const short8*)(
                    &Vt[brow * 64 + (((ks2 * 4 + quad) ^ (brow & 7)) << 3)]);
                oacc[db] = __builtin_amdgcn_mfma_f32_16x16x32_bf16(
                    pf, vf, oacc[db], 0, 0, 0);
            }
            lacc = __builtin_amdgcn_mfma_f32_16x16x32_bf16(
                pf, ones, lacc, 0, 0, 0);
        }
    }

    // ---- epilogue: O / l -> AO [B,S,1024] bf16 ----
    float inv[4];
#pragma unroll
    for (int r = 0; r < 4; r++) inv[r] = 1.f / lacc[r];
#pragma unroll
    for (int db = 0; db < 4; db++) {
        int d = db * 16 + r15;
#pragma unroll
        for (int r = 0; r < 4; r++) {
            int qi = q0 + wave * 16 + quad * 4 + r;
            AO[((size_t)(b_ * 2048 + qi) << 10) + h * 64 + d] =
                f2bf(oacc[db][r] * inv[r]);
        }
    }
}

__global__ void copy_u4(const uint4* __restrict__ src, uint4* __restrict__ dst) {
    size_t i = (size_t)blockIdx.x * 256 + threadIdx.x;
    dst[i] = src[i];
}

// ---------------------------------------------------------------------------
extern "C" void kernel_launch(void* const* d_in, const int* in_sizes, int n_in,
                              void* d_out, int out_size, void* d_ws, size_t ws_size,
                              hipStream_t stream)
{
    const void* x  = d_in[0];
    const void* Wq = d_in[1];
    const void* bq = d_in[2];
    const void* Wk = d_in[3];
    const void* bk = d_in[4];
    const void* Wv = d_in[5];
    const void* bv = d_in[6];
    const void* Wo = d_in[7];
    const void* bo = d_in[8];

    // ws: [flag, pad 256B][Kw 8MB][Vw(V^T) 8MB][AOw 8MB if ws_size allows]
    const size_t TEN = (size_t)2 * 16 * 2048 * 64;   // 4 Mi elements (8 MB)
    int*    flagp = (int*)d_ws;
    ushort* Kw    = (ushort*)((char*)d_ws + 256);
    ushort* Vw    = Kw + TEN;
    const bool big_ws = ws_size >= 3 * TEN * sizeof(ushort) + 256;
    ushort* AOw   = big_ws ? (Vw + TEN) : (ushort*)d_out;
    ushort* Oin   = big_ws ? AOw : Kw;    // O-proj input (Kw reused if small ws)

    detect_dtype<<<1, 256, 0, stream>>>((const ushort*)x, flagp);

    // K -> Kw [B,H,S,D] (pm=1) and V -> Vw [B,H,D,S] (pm=2) in ONE dispatch
    gemm_bt<<<dim3(32, 16, 2), dim3(512), 0, stream>>>(
        x, Wk, Wv, bk, bv, Kw, Vw, /*pa=*/1, /*pb=*/2, /*a_ext=*/1,
        /*out_ext=*/0, flagp);

    // fused Q-proj + attention -> AO (grid bh-major for XCD K/V^T locality)
    attn_fused<<<dim3(32, 16), dim3(512), 0, stream>>>(
        x, Wq, bq, Kw, Vw, AOw, flagp);

    // small-ws fallback: move AO out of d_out so O-proj is race-free
    if (!big_ws)
        copy_u4<<<dim3(2048), dim3(256), 0, stream>>>(
            (const uint4*)d_out, (uint4*)Oin);

    // O-projection -> final output (dtype per flag)
    gemm_bt<<<dim3(32, 16, 1), dim3(512), 0, stream>>>(
        Oin, Wo, Wo, bo, bo, d_out, d_out, /*pa=*/0, /*pb=*/0, /*a_ext=*/0,
        /*out_ext=*/1, flagp);
}